// Round 12
// baseline (178.591 us; speedup 1.0000x reference)
//
#include <hip/hip_runtime.h>
#include <math.h>

#define B_SZ 16384
#define NQ 10
#define DEPTH 6

typedef float f32x2 __attribute__((ext_vector_type(2)));

__device__ __forceinline__ f32x2 bc(float x){ return (f32x2){x, x}; }
__device__ __forceinline__ f32x2 fma2(f32x2 a, f32x2 b, f32x2 c){
  return __builtin_elementwise_fma(a, b, c);
}

// ---- constexpr GF(2) tracking of the CNOT ring (sequential, matches ref) ----
struct Tables {
  int m[DEPTH][NQ];
  int R[DEPTH][NQ];
  int meas[NQ];
};
constexpr Tables make_tables(){
  Tables t{};
  int cols[NQ] = {}, rows[NQ] = {};
  for (int i = 0; i < NQ; ++i){ cols[i] = 1 << i; rows[i] = 1 << i; }
  for (int d = 0; d < DEPTH; ++d){
    for (int q = 0; q < NQ; ++q){ t.m[d][q] = cols[q]; t.R[d][q] = rows[q]; }
    for (int c = 0; c < NQ; ++c){
      int tt = (c + 1) % NQ;
      cols[c]  ^= cols[tt];
      rows[tt] ^= rows[c];
    }
  }
  for (int q = 0; q < NQ; ++q) t.meas[q] = rows[q];
  return t;
}
constexpr Tables TAB = make_tables();

// ---- storage-basis change Phi (R9, proven) ----
constexpr int SM(int m){
  return (m & 0xF) | (((m >> 5) & 0xF) << 4) | (((m >> 9) & 1) << 8)
       | ((__builtin_popcount(m) & 1) << 9);
}
constexpr int FT(int F){
  int a4  = (F >> 4) & 1;
  int lo  = (F & 0xF)        ^ (a4 ? 0xF : 0);
  int mid = ((F >> 5) & 0xF) ^ (a4 ? 0xF : 0);
  int b8  = ((F >> 9) & 1) ^ a4;
  return lo | (mid << 4) | (b8 << 8) | (a4 << 9);
}

// ---- monotone float<->uint key for atomicMax over signed floats ----
__device__ __forceinline__ unsigned fkey(float x){
  unsigned b = __float_as_uint(x);
  return (b & 0x80000000u) ? ~b : (b | 0x80000000u);
}
__device__ __forceinline__ float funkey(unsigned k){
  unsigned b = (k & 0x80000000u) ? (k ^ 0x80000000u) : ~k;
  return __uint_as_float(b);
}

// ======== lane-xor machinery: DPP for masks 1..15, ds_bpermute otherwise ====
constexpr int quadctl(int m){ return (0^m) | ((1^m)<<2) | ((2^m)<<4) | ((3^m)<<6); }

template<int CTRL>
__device__ __forceinline__ float dppf(float x){
  return __uint_as_float((unsigned)__builtin_amdgcn_update_dpp(
      0, (int)__float_as_uint(x), CTRL, 0xF, 0xF, true));
}
template<int LM>   // 1..15 only
__device__ __forceinline__ float lxs(float x){
  if constexpr (LM == 0){
    return x;
  } else if constexpr (LM <= 3){
    return dppf<quadctl(LM)>(x);
  } else if constexpr (LM == 7){
    return dppf<0x141>(x);
  } else if constexpr (LM == 8){
    return dppf<0x128>(x);
  } else if constexpr (LM == 15){
    return dppf<0x140>(x);
  } else if constexpr ((LM & 12) == 4){
    return lxs<LM ^ 7>(dppf<0x141>(x));
  } else if constexpr ((LM & 12) == 8){
    return lxs<LM ^ 8>(dppf<0x128>(x));
  } else {
    return lxs<LM ^ 15>(dppf<0x140>(x));
  }
}
template<int LM>
__device__ __forceinline__ f32x2 lx2(f32x2 v){
  f32x2 r;
  r.x = lxs<LM>(v.x);
  r.y = lxs<LM>(v.y);
  return r;
}
__device__ __forceinline__ f32x2 lxd2(int adr, f32x2 v){
  f32x2 r;
  r.x = __uint_as_float((unsigned)__builtin_amdgcn_ds_bpermute(adr, (int)__float_as_uint(v.x)));
  r.y = __uint_as_float((unsigned)__builtin_amdgcn_ds_bpermute(adr, (int)__float_as_uint(v.y)));
  return r;
}

// ---- prep ----
__global__ __launch_bounds__(256) void k_prep(const float* __restrict__ wts,
    const float* __restrict__ fcW,
    float4* __restrict__ U0,     // 20
    float* __restrict__ gcT,     // 50: tan(ax)
    float2* __restrict__ phase,  // 4*1024: (c,s) per storage index, layers 1..4
    float* __restrict__ fcWs,    // 40: fcW * (prod cos)^2
    unsigned* __restrict__ gkey)
{
  int idx = blockIdx.x * 256 + threadIdx.x;
  if (idx < 4096){
    int layer = 1 + (idx >> 10);
    int p = idx & 1023;          // STORAGE index
    float phi = 0.f;
    for (int q = 0; q < NQ; ++q){
      float az = wts[(layer*NQ + q)*2 + 1] * 0.5f;
      int Fs = FT(TAB.R[layer][q]);
      phi += (__popc(Fs & p) & 1) ? az : -az;
    }
    phase[idx] = make_float2(cosf(phi), sinf(phi));
  }
  if (blockIdx.x == 0){
    int t = threadIdx.x;
    if (t < NQ){
      float ax = wts[t*2+0]*0.5f, az = wts[t*2+1]*0.5f;
      float ca=cosf(ax), sa=sinf(ax), cz=cosf(az), sz=sinf(az);
      U0[t*2+0] = make_float4(ca*cz, -ca*sz, -sa*sz, -sa*cz);
      U0[t*2+1] = make_float4(sa*sz, -sa*cz,  ca*cz,  ca*sz);
    } else if (t >= 64 && t < 64 + 50){
      int g = t - 64;
      int d = 1 + g/10, q = g % 10;
      float ax = wts[(d*NQ+q)*2+0]*0.5f;
      gcT[g] = tanf(ax);
    } else if (t == 120){
      *gkey = 0u;
    } else if (t == 121){
      float pc = 1.f;
      for (int g = 0; g < 50; ++g){
        int d = 1 + g/10, q = g % 10;
        pc *= cosf(wts[(d*NQ+q)*2+0]*0.5f);
      }
      float s2 = pc * pc;
      for (int j = 0; j < 40; ++j) fcWs[j] = fcW[j] * s2;
    }
  }
}

// ---- K1: coalesced LDS-staged pool -> encode -> global max (R10, proven) ----
__global__ __launch_bounds__(256) void k1_encode(const float* __restrict__ x,
    const float* __restrict__ encW, const float* __restrict__ encB,
    float* __restrict__ encOut, unsigned* __restrict__ gkey)
{
  __shared__ float lds[4][788];
  __shared__ float poolS[4][16];
  __shared__ float wmax[4];
  int tid = threadIdx.x, lane = tid & 63, wid = tid >> 6;
  float bm = -INFINITY;

  #pragma unroll 1
  for (int it = 0; it < 4; ++it){
    int s = blockIdx.x * 16 + it * 4 + wid;
    const float4* xs4 = reinterpret_cast<const float4*>(x + (size_t)s * 784);
    float4* l4 = reinterpret_cast<float4*>(lds[wid]);
    l4[lane]       = xs4[lane];
    l4[lane + 64]  = xs4[lane + 64];
    l4[lane + 128] = xs4[lane + 128];
    if (lane < 4) l4[lane + 192] = xs4[lane + 192];
    __syncthreads();
    int b = lane & 15, sub = lane >> 4;
    int r0 = (b >> 2) * 6, c0 = (b & 3) * 6;
    float acc = 0.f;
    #pragma unroll
    for (int k = 0; k < 9; ++k){
      int e = sub * 9 + k;
      acc += lds[wid][(r0 + e / 6) * 28 + c0 + e % 6];
    }
    acc += __shfl_xor(acc, 16, 64);
    acc += __shfl_xor(acc, 32, 64);
    if (lane < 16) poolS[wid][lane] = acc * (1.f/36.f);
    __syncthreads();
    float ev = -INFINITY;
    if (lane < NQ){
      float e = encB[lane];
      #pragma unroll
      for (int k = 0; k < 16; ++k) e = fmaf(poolS[wid][k], encW[lane*16+k], e);
      encOut[(size_t)s*NQ + lane] = e;
      ev = e;
    }
    #pragma unroll
    for (int st = 1; st < 16; st <<= 1) ev = fmaxf(ev, __shfl_xor(ev, st, 64));
    bm = fmaxf(bm, ev);
  }
  if (lane == 0) wmax[wid] = bm;
  __syncthreads();
  if (tid == 0){
    float mm = fmaxf(fmaxf(wmax[0], wmax[1]), fmaxf(wmax[2], wmax[3]));
    atomicMax(gkey, fkey(mm));
  }
}

// ---- chain init: product state in storage basis (R9, proven) ----
__device__ __forceinline__ void init_chain(const float* __restrict__ enc,
    const float4* __restrict__ U0, float invr, int sA, int sB, int lane,
    f32x2 (&re)[16], f32x2 (&im)[16])
{
  f32x2 lr, li;
  #pragma unroll
  for (int j = 0; j < 5; ++j){
    int q = (j < 4) ? (5 + j) : 9;
    float angA = enc[(size_t)sA*NQ + q] * invr;
    float angB = enc[(size_t)sB*NQ + q] * invr;
    f32x2 cv = {__cosf(angA), __cosf(angB)};
    f32x2 sv = {__sinf(angA), __sinf(angB)};
    float4 a = U0[q*2+0], b = U0[q*2+1];
    f32x2 pa_r = fma2(bc(a.z), sv, bc(a.x)*cv);
    f32x2 pa_i = fma2(bc(a.w), sv, bc(a.y)*cv);
    f32x2 pb_r = fma2(bc(b.z), sv, bc(b.x)*cv);
    f32x2 pb_i = fma2(bc(b.w), sv, bc(b.y)*cv);
    bool bit = (lane >> j) & 1;
    f32x2 fr = bit ? pb_r : pa_r;
    f32x2 fi = bit ? pb_i : pa_i;
    if (j == 0){ lr = fr; li = fi; }
    else {
      f32x2 t = lr*fr - li*fi;
      li = fma2(lr, fi, li*fr);
      lr = t;
    }
  }
  f32x2 A0r, A0i, A1r, A1i;
  {
    float angA = enc[(size_t)sA*NQ + 4] * invr;
    float angB = enc[(size_t)sB*NQ + 4] * invr;
    f32x2 cv = {__cosf(angA), __cosf(angB)};
    f32x2 sv = {__sinf(angA), __sinf(angB)};
    float4 a = U0[8], b = U0[9];
    f32x2 pa_r = fma2(bc(a.z), sv, bc(a.x)*cv);
    f32x2 pa_i = fma2(bc(a.w), sv, bc(a.y)*cv);
    f32x2 pb_r = fma2(bc(b.z), sv, bc(b.x)*cv);
    f32x2 pb_i = fma2(bc(b.w), sv, bc(b.y)*cv);
    bool e = __popc(lane) & 1;
    A0r = e ? pb_r : pa_r;  A0i = e ? pb_i : pa_i;
    A1r = e ? pa_r : pb_r;  A1i = e ? pa_i : pb_i;
  }
  re[0] = lr; im[0] = li;
  #pragma unroll
  for (int k = 0; k < 4; ++k){
    float angA = enc[(size_t)sA*NQ + k] * invr;
    float angB = enc[(size_t)sB*NQ + k] * invr;
    f32x2 cv = {__cosf(angA), __cosf(angB)};
    f32x2 sv = {__sinf(angA), __sinf(angB)};
    float4 a = U0[k*2+0], b = U0[k*2+1];
    f32x2 pa_r = fma2(bc(a.z), sv, bc(a.x)*cv);
    f32x2 pa_i = fma2(bc(a.w), sv, bc(a.y)*cv);
    f32x2 pb_r = fma2(bc(b.z), sv, bc(b.x)*cv);
    f32x2 pb_i = fma2(bc(b.w), sv, bc(b.y)*cv);
    int w = 1 << k;
    #pragma unroll
    for (int r = 0; r < 8; ++r) if (r < w){
      f32x2 xr = re[r], xi = im[r];
      re[r|w] = xr*pb_r - xi*pb_i;
      im[r|w] = fma2(xr, pb_i, xi*pb_r);
      re[r]   = xr*pa_r - xi*pa_i;
      im[r]   = fma2(xr, pa_i, xi*pa_r);
    }
  }
  #pragma unroll
  for (int r = 0; r < 16; ++r){
    f32x2 sr = (__builtin_popcount(r) & 1) ? A1r : A0r;
    f32x2 si = (__builtin_popcount(r) & 1) ? A1i : A0i;
    f32x2 xr = re[r], xi = im[r];
    re[r] = xr*sr - xi*si;
    im[r] = fma2(xr, si, xi*sr);
  }
}

// ---- Rx gate on TWO independent chains (ILP): tangent form, storage basis ----
template<int D, int Q>
__device__ __forceinline__ void rx_gate2(
    f32x2 (&reA)[16], f32x2 (&imA)[16],
    f32x2 (&reB)[16], f32x2 (&imB)[16],
    const float* __restrict__ gcT, int lane)
{
  constexpr int ms = SM(TAB.m[D][Q]);
  constexpr int rm = ms & 15;
  constexpr int lm = (ms >> 4) & 63;
  float Tt = gcT[(D-1)*NQ + Q];
  f32x2 T = bc(Tt), nT = bc(-Tt);

  if constexpr (lm == 0){
    constexpr int lb = rm & (-rm);
    #pragma unroll
    for (int r = 0; r < 16; ++r) if (!(r & lb)){
      int r2 = r ^ rm;
      f32x2 ar = reA[r],  ai = imA[r];
      f32x2 br = reA[r2], bi = imA[r2];
      reA[r]  = fma2(T,  bi, ar);
      imA[r]  = fma2(nT, br, ai);
      reA[r2] = fma2(T,  ai, br);
      imA[r2] = fma2(nT, ar, bi);
      f32x2 cr = reB[r],  ci = imB[r];
      f32x2 dr = reB[r2], di = imB[r2];
      reB[r]  = fma2(T,  di, cr);
      imB[r]  = fma2(nT, dr, ci);
      reB[r2] = fma2(T,  ci, dr);
      imB[r2] = fma2(nT, cr, di);
    }
  } else if constexpr (lm < 16){
    if constexpr (rm == 0){
      #pragma unroll
      for (int r = 0; r < 16; ++r){
        f32x2 biA = lx2<lm>(imA[r]);
        f32x2 brA = lx2<lm>(reA[r]);
        f32x2 biB = lx2<lm>(imB[r]);
        f32x2 brB = lx2<lm>(reB[r]);
        reA[r] = fma2(T,  biA, reA[r]);
        imA[r] = fma2(nT, brA, imA[r]);
        reB[r] = fma2(T,  biB, reB[r]);
        imB[r] = fma2(nT, brB, imB[r]);
      }
    } else {
      constexpr int lb = rm & (-rm);
      #pragma unroll
      for (int r = 0; r < 16; ++r) if (!(r & lb)){
        int r2 = r ^ rm;
        f32x2 bi2A = lx2<lm>(imA[r2]);
        f32x2 br2A = lx2<lm>(reA[r2]);
        f32x2 bi1A = lx2<lm>(imA[r]);
        f32x2 br1A = lx2<lm>(reA[r]);
        f32x2 bi2B = lx2<lm>(imB[r2]);
        f32x2 br2B = lx2<lm>(reB[r2]);
        f32x2 bi1B = lx2<lm>(imB[r]);
        f32x2 br1B = lx2<lm>(reB[r]);
        reA[r]  = fma2(T,  bi2A, reA[r]);
        imA[r]  = fma2(nT, br2A, imA[r]);
        reA[r2] = fma2(T,  bi1A, reA[r2]);
        imA[r2] = fma2(nT, br1A, imA[r2]);
        reB[r]  = fma2(T,  bi2B, reB[r]);
        imB[r]  = fma2(nT, br2B, imB[r]);
        reB[r2] = fma2(T,  bi1B, reB[r2]);
        imB[r2] = fma2(nT, br1B, imB[r2]);
      }
    }
  } else {
    const int adr = (lane ^ lm) << 2;
    if constexpr (rm == 0){
      #pragma unroll
      for (int r = 0; r < 16; ++r){
        f32x2 biA = lxd2(adr, imA[r]);
        f32x2 brA = lxd2(adr, reA[r]);
        f32x2 biB = lxd2(adr, imB[r]);
        f32x2 brB = lxd2(adr, reB[r]);
        reA[r] = fma2(T,  biA, reA[r]);
        imA[r] = fma2(nT, brA, imA[r]);
        reB[r] = fma2(T,  biB, reB[r]);
        imB[r] = fma2(nT, brB, imB[r]);
      }
    } else {
      constexpr int lb = rm & (-rm);
      #pragma unroll
      for (int r = 0; r < 16; ++r) if (!(r & lb)){
        int r2 = r ^ rm;
        f32x2 bi2A = lxd2(adr, imA[r2]);
        f32x2 br2A = lxd2(adr, reA[r2]);
        f32x2 bi1A = lxd2(adr, imA[r]);
        f32x2 br1A = lxd2(adr, reA[r]);
        f32x2 bi2B = lxd2(adr, imB[r2]);
        f32x2 br2B = lxd2(adr, reB[r2]);
        f32x2 bi1B = lxd2(adr, imB[r]);
        f32x2 br1B = lxd2(adr, reB[r]);
        reA[r]  = fma2(T,  bi2A, reA[r]);
        imA[r]  = fma2(nT, br2A, imA[r]);
        reA[r2] = fma2(T,  bi1A, reA[r2]);
        imA[r2] = fma2(nT, br1A, imA[r2]);
        reB[r]  = fma2(T,  bi2B, reB[r]);
        imB[r]  = fma2(nT, br2B, imB[r]);
        reB[r2] = fma2(T,  bi1B, reB[r2]);
        imB[r2] = fma2(nT, br1B, imB[r2]);
      }
    }
  }
}

template<int D>
__device__ __forceinline__ void run_layer2(
    f32x2 (&reA)[16], f32x2 (&imA)[16],
    f32x2 (&reB)[16], f32x2 (&imB)[16],
    const float* __restrict__ gcT, const float2* __restrict__ phase2, int lane)
{
  rx_gate2<D,0>(reA, imA, reB, imB, gcT, lane);
  rx_gate2<D,1>(reA, imA, reB, imB, gcT, lane);
  rx_gate2<D,2>(reA, imA, reB, imB, gcT, lane);
  rx_gate2<D,3>(reA, imA, reB, imB, gcT, lane);
  rx_gate2<D,4>(reA, imA, reB, imB, gcT, lane);
  rx_gate2<D,5>(reA, imA, reB, imB, gcT, lane);
  rx_gate2<D,6>(reA, imA, reB, imB, gcT, lane);
  rx_gate2<D,7>(reA, imA, reB, imB, gcT, lane);
  rx_gate2<D,8>(reA, imA, reB, imB, gcT, lane);
  rx_gate2<D,9>(reA, imA, reB, imB, gcT, lane);
  if constexpr (D <= 4){
    const float2* __restrict__ pp = phase2 + (size_t)(D-1)*1024 + lane*16;
    #pragma unroll
    for (int r = 0; r < 16; ++r){
      float2 ph = pp[r];                  // SAME diagonal for both chains
      f32x2 cp = bc(ph.x), sp = bc(ph.y);
      f32x2 ar = reA[r], ai = imA[r];
      reA[r] = fma2(-sp, ai, cp*ar);
      imA[r] = fma2( sp, ar, cp*ai);
      f32x2 br = reB[r], bi = imB[r];
      reB[r] = fma2(-sp, bi, cp*br);
      imB[r] = fma2( sp, br, cp*bi);
    }
  }
}

// ---- measurement + fused FC for one chain ----
__device__ __forceinline__ void measure_fc(
    f32x2 (&re)[16], f32x2 (&im)[16],
    const float* __restrict__ fcWs, int lane, f32x2 (&o2)[4])
{
  f32x2 p2[16];
  #pragma unroll
  for (int r = 0; r < 16; ++r) p2[r] = fma2(re[r], re[r], im[r]*im[r]);
  #pragma unroll
  for (int k = 0; k < 4; ++k){
    int w = 1 << k;
    #pragma unroll
    for (int r = 0; r < 16; ++r) if (!(r & w)){
      f32x2 a = p2[r], b = p2[r|w];
      p2[r] = a + b; p2[r|w] = a - b;
    }
  }
  #pragma unroll
  for (int j = 0; j < 4; ++j) o2[j] = (f32x2){0.f, 0.f};
  #pragma unroll
  for (int q = 0; q < NQ; ++q){
    constexpr int RALL[NQ] = {FT(TAB.meas[0]),FT(TAB.meas[1]),FT(TAB.meas[2]),
                              FT(TAB.meas[3]),FT(TAB.meas[4]),FT(TAB.meas[5]),
                              FT(TAB.meas[6]),FT(TAB.meas[7]),FT(TAB.meas[8]),
                              FT(TAB.meas[9])};
    int R = RALL[q];
    f32x2 tq = p2[R & 15];
    unsigned sg = (unsigned)(__popc((R >> 4) & lane) << 31);
    tq.x = __uint_as_float(__float_as_uint(tq.x) ^ sg);
    tq.y = __uint_as_float(__float_as_uint(tq.y) ^ sg);
    #pragma unroll
    for (int j = 0; j < 4; ++j) o2[j] = fma2(tq, bc(fcWs[j*NQ + q]), o2[j]);
  }
  #pragma unroll
  for (int j = 0; j < 4; ++j){
    #pragma unroll
    for (int st = 1; st < 64; st <<= 1){
      o2[j].x += __shfl_xor(o2[j].x, st, 64);
      o2[j].y += __shfl_xor(o2[j].y, st, 64);
    }
  }
}

// ---- K2: one wave per FOUR samples (two independent packed chains) ----
__global__ __launch_bounds__(256) void k2_qsim(
    const float* __restrict__ enc, const unsigned* __restrict__ gkey,
    const float4* __restrict__ U0, const float* __restrict__ gcT,
    const float2* __restrict__ phase2,
    const float* __restrict__ fcWs, const float* __restrict__ fcB,
    float* __restrict__ outB)
{
  int tid  = threadIdx.x;
  int lane = tid & 63;
  int wid  = tid >> 6;
  int s0   = blockIdx.x * 16 + wid * 4;

  float invr = 3.14159265358979f / (funkey(*gkey) + 1e-8f);

  f32x2 reA[16], imA[16], reB[16], imB[16];
  init_chain(enc, U0, invr, s0,     s0 + 1, lane, reA, imA);
  init_chain(enc, U0, invr, s0 + 2, s0 + 3, lane, reB, imB);

  run_layer2<1>(reA, imA, reB, imB, gcT, phase2, lane);
  run_layer2<2>(reA, imA, reB, imB, gcT, phase2, lane);
  run_layer2<3>(reA, imA, reB, imB, gcT, phase2, lane);
  run_layer2<4>(reA, imA, reB, imB, gcT, phase2, lane);
  run_layer2<5>(reA, imA, reB, imB, gcT, phase2, lane);

  f32x2 oA[4], oB[4];
  measure_fc(reA, imA, fcWs, lane, oA);
  measure_fc(reB, imB, fcWs, lane, oB);

  if (lane == 0){
    float4 w0 = make_float4(oA[0].x+fcB[0], oA[1].x+fcB[1], oA[2].x+fcB[2], oA[3].x+fcB[3]);
    float4 w1 = make_float4(oA[0].y+fcB[0], oA[1].y+fcB[1], oA[2].y+fcB[2], oA[3].y+fcB[3]);
    float4 w2 = make_float4(oB[0].x+fcB[0], oB[1].x+fcB[1], oB[2].x+fcB[2], oB[3].x+fcB[3]);
    float4 w3 = make_float4(oB[0].y+fcB[0], oB[1].y+fcB[1], oB[2].y+fcB[2], oB[3].y+fcB[3]);
    float4* ob = reinterpret_cast<float4*>(&outB[(size_t)s0*4]);
    ob[0] = w0; ob[1] = w1; ob[2] = w2; ob[3] = w3;
  }
}

// ---- K3: deterministic BN stats (single block) ----
__global__ __launch_bounds__(1024) void k3_stats(const float* __restrict__ outB,
                                                 float* __restrict__ stats)
{
  int tid = threadIdx.x;
  float sum[4] = {0,0,0,0}, sq[4] = {0,0,0,0};
  for (int row = tid; row < B_SZ; row += 1024){
    float4 v = *reinterpret_cast<const float4*>(outB + (size_t)row*4);
    sum[0]+=v.x; sq[0]+=v.x*v.x;
    sum[1]+=v.y; sq[1]+=v.y*v.y;
    sum[2]+=v.z; sq[2]+=v.z*v.z;
    sum[3]+=v.w; sq[3]+=v.w*v.w;
  }
  #pragma unroll
  for (int k = 0; k < 4; ++k){
    #pragma unroll
    for (int st = 1; st < 64; st <<= 1){
      sum[k] += __shfl_xor(sum[k], st, 64);
      sq[k]  += __shfl_xor(sq[k],  st, 64);
    }
  }
  __shared__ float ls[16][8];
  int lane = tid & 63, w = tid >> 6;
  if (lane == 0){
    #pragma unroll
    for (int k = 0; k < 4; ++k){ ls[w][k] = sum[k]; ls[w][4+k] = sq[k]; }
  }
  __syncthreads();
  if (tid == 0){
    float fs[8];
    #pragma unroll
    for (int k = 0; k < 8; ++k){
      float a = 0.f;
      for (int w2 = 0; w2 < 16; ++w2) a += ls[w2][k];
      fs[k] = a;
    }
    #pragma unroll
    for (int k = 0; k < 4; ++k){
      float mean = fs[k] * (1.f/B_SZ);
      float var  = fs[4+k] * (1.f/B_SZ) - mean*mean;
      stats[k]   = mean;
      stats[4+k] = rsqrtf(var + 1e-5f);
    }
  }
}

// ---- K4: apply BN ----
__global__ __launch_bounds__(256) void k4_bn(const float* __restrict__ outB,
    const float* __restrict__ stats, const float* __restrict__ gamma,
    const float* __restrict__ beta, float* __restrict__ out)
{
  int idx = blockIdx.x * 256 + threadIdx.x;
  int c = idx & 3;
  float v = outB[idx];
  out[idx] = gamma[c] * (v - stats[c]) * stats[4+c] + beta[c];
}

extern "C" void kernel_launch(void* const* d_in, const int* in_sizes, int n_in,
                              void* d_out, int out_size, void* d_ws, size_t ws_size,
                              hipStream_t stream)
{
  const float* x     = (const float*)d_in[0];
  const float* encW  = (const float*)d_in[1];
  const float* encB  = (const float*)d_in[2];
  const float* wts   = (const float*)d_in[3];
  const float* fcW   = (const float*)d_in[4];
  const float* fcB   = (const float*)d_in[5];
  const float* gamma = (const float*)d_in[6];
  const float* beta  = (const float*)d_in[7];

  char* ws = (char*)d_ws;
  unsigned* gkey  = (unsigned*)ws;                      // 4 B
  float4*  U0     = (float4*)(ws + 256);                // 320 B
  float*   gcT    = (float*)(ws + 1024);                // 200 B
  float*   fcWs   = (float*)(ws + 2048);                // 160 B
  float2*  phase  = (float2*)(ws + 4096);               // 32 KB (c,s)
  float*   enc    = (float*)(ws + 4096 + 65536);
  float*   outB   = (float*)(ws + 4096 + 65536 + (size_t)B_SZ*NQ*4);
  float*   stats  = (float*)(ws + 4096 + 65536 + (size_t)B_SZ*NQ*4 + (size_t)B_SZ*4*4);

  hipLaunchKernelGGL(k_prep, dim3(16), dim3(256), 0, stream, wts, fcW, U0, gcT, phase, fcWs, gkey);
  hipLaunchKernelGGL(k1_encode, dim3(B_SZ/16), dim3(256), 0, stream,
                     x, encW, encB, enc, gkey);
  hipLaunchKernelGGL(k2_qsim, dim3(B_SZ/16), dim3(256), 0, stream,
                     enc, gkey, U0, gcT, phase, fcWs, fcB, outB);
  hipLaunchKernelGGL(k3_stats, dim3(1), dim3(1024), 0, stream, outB, stats);
  hipLaunchKernelGGL(k4_bn, dim3(B_SZ*4/256), dim3(256), 0, stream,
                     outB, stats, gamma, beta, (float*)d_out);
}

// Round 13
// 173.801 us; speedup vs baseline: 1.0276x; 1.0276x over previous
//
#include <hip/hip_runtime.h>
#include <math.h>

#define B_SZ 16384
#define NQ 10
#define DEPTH 6

typedef float f32x2 __attribute__((ext_vector_type(2)));

__device__ __forceinline__ f32x2 bc(float x){ return (f32x2){x, x}; }
__device__ __forceinline__ f32x2 fma2(f32x2 a, f32x2 b, f32x2 c){
  return __builtin_elementwise_fma(a, b, c);
}

// ---- constexpr GF(2) tracking of the CNOT ring (sequential, matches ref) ----
struct Tables {
  int m[DEPTH][NQ];
  int R[DEPTH][NQ];
  int meas[NQ];
};
constexpr Tables make_tables(){
  Tables t{};
  int cols[NQ] = {}, rows[NQ] = {};
  for (int i = 0; i < NQ; ++i){ cols[i] = 1 << i; rows[i] = 1 << i; }
  for (int d = 0; d < DEPTH; ++d){
    for (int q = 0; q < NQ; ++q){ t.m[d][q] = cols[q]; t.R[d][q] = rows[q]; }
    for (int c = 0; c < NQ; ++c){
      int tt = (c + 1) % NQ;
      cols[c]  ^= cols[tt];
      rows[tt] ^= rows[c];
    }
  }
  for (int q = 0; q < NQ; ++q) t.meas[q] = rows[q];
  return t;
}
constexpr Tables TAB = make_tables();

// ---- storage-basis change Phi (R9, proven) ----
constexpr int SM(int m){
  return (m & 0xF) | (((m >> 5) & 0xF) << 4) | (((m >> 9) & 1) << 8)
       | ((__builtin_popcount(m) & 1) << 9);
}
constexpr int FT(int F){
  int a4  = (F >> 4) & 1;
  int lo  = (F & 0xF)        ^ (a4 ? 0xF : 0);
  int mid = ((F >> 5) & 0xF) ^ (a4 ? 0xF : 0);
  int b8  = ((F >> 9) & 1) ^ a4;
  return lo | (mid << 4) | (b8 << 8) | (a4 << 9);
}

// ---- monotone float<->uint key for atomicMax over signed floats ----
__device__ __forceinline__ unsigned fkey(float x){
  unsigned b = __float_as_uint(x);
  return (b & 0x80000000u) ? ~b : (b | 0x80000000u);
}
__device__ __forceinline__ float funkey(unsigned k){
  unsigned b = (k & 0x80000000u) ? (k ^ 0x80000000u) : ~k;
  return __uint_as_float(b);
}

// ======== lane-xor machinery: DPP for masks 1..15, ds_bpermute otherwise ====
constexpr int quadctl(int m){ return (0^m) | ((1^m)<<2) | ((2^m)<<4) | ((3^m)<<6); }

template<int CTRL>
__device__ __forceinline__ float dppf(float x){
  return __uint_as_float((unsigned)__builtin_amdgcn_update_dpp(
      0, (int)__float_as_uint(x), CTRL, 0xF, 0xF, true));
}
template<int LM>   // 1..15 only
__device__ __forceinline__ float lxs(float x){
  if constexpr (LM == 0){
    return x;
  } else if constexpr (LM <= 3){
    return dppf<quadctl(LM)>(x);
  } else if constexpr (LM == 7){
    return dppf<0x141>(x);
  } else if constexpr (LM == 8){
    return dppf<0x128>(x);
  } else if constexpr (LM == 15){
    return dppf<0x140>(x);
  } else if constexpr ((LM & 12) == 4){
    return lxs<LM ^ 7>(dppf<0x141>(x));
  } else if constexpr ((LM & 12) == 8){
    return lxs<LM ^ 8>(dppf<0x128>(x));
  } else {
    return lxs<LM ^ 15>(dppf<0x140>(x));
  }
}
template<int LM>
__device__ __forceinline__ f32x2 lx2(f32x2 v){
  f32x2 r;
  r.x = lxs<LM>(v.x);
  r.y = lxs<LM>(v.y);
  return r;
}
__device__ __forceinline__ f32x2 lxd2(int adr, f32x2 v){
  f32x2 r;
  r.x = __uint_as_float((unsigned)__builtin_amdgcn_ds_bpermute(adr, (int)__float_as_uint(v.x)));
  r.y = __uint_as_float((unsigned)__builtin_amdgcn_ds_bpermute(adr, (int)__float_as_uint(v.y)));
  return r;
}

// ---- prep ----
__global__ __launch_bounds__(256) void k_prep(const float* __restrict__ wts,
    const float* __restrict__ fcW,
    float4* __restrict__ U0,     // 20
    float* __restrict__ gcT,     // 50: tan(ax)
    float4* __restrict__ phase,  // 4*1024: (c,c,s,s) per storage index
    float* __restrict__ fcWs,    // 40: fcW * (prod cos)^2
    unsigned* __restrict__ gkey)
{
  int idx = blockIdx.x * 256 + threadIdx.x;
  if (idx < 4096){
    int layer = 1 + (idx >> 10);
    int p = idx & 1023;          // STORAGE index
    float phi = 0.f;
    for (int q = 0; q < NQ; ++q){
      float az = wts[(layer*NQ + q)*2 + 1] * 0.5f;
      int Fs = FT(TAB.R[layer][q]);
      phi += (__popc(Fs & p) & 1) ? az : -az;
    }
    float c = cosf(phi), s = sinf(phi);
    phase[idx] = make_float4(c, c, s, s);
  }
  if (blockIdx.x == 0){
    int t = threadIdx.x;
    if (t < NQ){
      float ax = wts[t*2+0]*0.5f, az = wts[t*2+1]*0.5f;
      float ca=cosf(ax), sa=sinf(ax), cz=cosf(az), sz=sinf(az);
      U0[t*2+0] = make_float4(ca*cz, -ca*sz, -sa*sz, -sa*cz);
      U0[t*2+1] = make_float4(sa*sz, -sa*cz,  ca*cz,  ca*sz);
    } else if (t >= 64 && t < 64 + 50){
      int g = t - 64;
      int d = 1 + g/10, q = g % 10;
      float ax = wts[(d*NQ+q)*2+0]*0.5f;
      gcT[g] = tanf(ax);
    } else if (t == 120){
      *gkey = 0u;
    } else if (t == 121){
      float pc = 1.f;
      for (int g = 0; g < 50; ++g){
        int d = 1 + g/10, q = g % 10;
        pc *= cosf(wts[(d*NQ+q)*2+0]*0.5f);
      }
      float s2 = pc * pc;
      for (int j = 0; j < 40; ++j) fcWs[j] = fcW[j] * s2;
    }
  }
}

// ---- K1: coalesced LDS-staged pool -> encode -> global max (R10, proven) ----
__global__ __launch_bounds__(256) void k1_encode(const float* __restrict__ x,
    const float* __restrict__ encW, const float* __restrict__ encB,
    float* __restrict__ encOut, unsigned* __restrict__ gkey)
{
  __shared__ float lds[4][788];
  __shared__ float poolS[4][16];
  __shared__ float wmax[4];
  int tid = threadIdx.x, lane = tid & 63, wid = tid >> 6;
  float bm = -INFINITY;

  #pragma unroll 1
  for (int it = 0; it < 4; ++it){
    int s = blockIdx.x * 16 + it * 4 + wid;
    const float4* xs4 = reinterpret_cast<const float4*>(x + (size_t)s * 784);
    float4* l4 = reinterpret_cast<float4*>(lds[wid]);
    l4[lane]       = xs4[lane];
    l4[lane + 64]  = xs4[lane + 64];
    l4[lane + 128] = xs4[lane + 128];
    if (lane < 4) l4[lane + 192] = xs4[lane + 192];
    __syncthreads();
    int b = lane & 15, sub = lane >> 4;
    int r0 = (b >> 2) * 6, c0 = (b & 3) * 6;
    float acc = 0.f;
    #pragma unroll
    for (int k = 0; k < 9; ++k){
      int e = sub * 9 + k;
      acc += lds[wid][(r0 + e / 6) * 28 + c0 + e % 6];
    }
    acc += __shfl_xor(acc, 16, 64);
    acc += __shfl_xor(acc, 32, 64);
    if (lane < 16) poolS[wid][lane] = acc * (1.f/36.f);
    __syncthreads();
    float ev = -INFINITY;
    if (lane < NQ){
      float e = encB[lane];
      #pragma unroll
      for (int k = 0; k < 16; ++k) e = fmaf(poolS[wid][k], encW[lane*16+k], e);
      encOut[(size_t)s*NQ + lane] = e;
      ev = e;
    }
    #pragma unroll
    for (int st = 1; st < 16; st <<= 1) ev = fmaxf(ev, __shfl_xor(ev, st, 64));
    bm = fmaxf(bm, ev);
  }
  if (lane == 0) wmax[wid] = bm;
  __syncthreads();
  if (tid == 0){
    float mm = fmaxf(fmaxf(wmax[0], wmax[1]), fmaxf(wmax[2], wmax[3]));
    atomicMax(gkey, fkey(mm));
  }
}

// ---- Rx gate, tangent form, storage basis (R9 tiers — measured best) ----
template<int D, int Q>
__device__ __forceinline__ void rx_gate(f32x2 (&re)[16], f32x2 (&im)[16],
    const float* __restrict__ gcT, int lane)
{
  constexpr int ms = SM(TAB.m[D][Q]);
  constexpr int rm = ms & 15;
  constexpr int lm = (ms >> 4) & 63;
  float Tt = gcT[(D-1)*NQ + Q];
  f32x2 T = bc(Tt), nT = bc(-Tt);

  if constexpr (lm == 0){
    constexpr int lb = rm & (-rm);
    #pragma unroll
    for (int r = 0; r < 16; ++r) if (!(r & lb)){
      int r2 = r ^ rm;
      f32x2 ar = re[r],  ai = im[r];
      f32x2 br = re[r2], bi = im[r2];
      re[r]  = fma2(T,  bi, ar);
      im[r]  = fma2(nT, br, ai);
      re[r2] = fma2(T,  ai, br);
      im[r2] = fma2(nT, ar, bi);
    }
  } else if constexpr (lm < 16){
    if constexpr (rm == 0){
      #pragma unroll
      for (int r = 0; r < 16; ++r){
        f32x2 bi = lx2<lm>(im[r]);
        f32x2 br = lx2<lm>(re[r]);
        re[r] = fma2(T,  bi, re[r]);
        im[r] = fma2(nT, br, im[r]);
      }
    } else {
      constexpr int lb = rm & (-rm);
      #pragma unroll
      for (int r = 0; r < 16; ++r) if (!(r & lb)){
        int r2 = r ^ rm;
        f32x2 bi2 = lx2<lm>(im[r2]);
        f32x2 br2 = lx2<lm>(re[r2]);
        f32x2 bi1 = lx2<lm>(im[r]);
        f32x2 br1 = lx2<lm>(re[r]);
        re[r]  = fma2(T,  bi2, re[r]);
        im[r]  = fma2(nT, br2, im[r]);
        re[r2] = fma2(T,  bi1, re[r2]);
        im[r2] = fma2(nT, br1, im[r2]);
      }
    }
  } else {
    const int adr = (lane ^ lm) << 2;
    if constexpr (rm == 0){
      #pragma unroll
      for (int r = 0; r < 16; ++r){
        f32x2 bi = lxd2(adr, im[r]);
        f32x2 br = lxd2(adr, re[r]);
        re[r] = fma2(T,  bi, re[r]);
        im[r] = fma2(nT, br, im[r]);
      }
    } else {
      constexpr int lb = rm & (-rm);
      #pragma unroll
      for (int r = 0; r < 16; ++r) if (!(r & lb)){
        int r2 = r ^ rm;
        f32x2 bi2 = lxd2(adr, im[r2]);
        f32x2 br2 = lxd2(adr, re[r2]);
        f32x2 bi1 = lxd2(adr, im[r]);
        f32x2 br1 = lxd2(adr, re[r]);
        re[r]  = fma2(T,  bi2, re[r]);
        im[r]  = fma2(nT, br2, im[r]);
        re[r2] = fma2(T,  bi1, re[r2]);
        im[r2] = fma2(nT, br1, im[r2]);
      }
    }
  }
}

template<int D>
__device__ __forceinline__ void run_layer(f32x2 (&re)[16], f32x2 (&im)[16],
    const float* __restrict__ gcT, const float4* __restrict__ phase4, int lane)
{
  float4 phv[16];
  if constexpr (D <= 4){
    const float4* __restrict__ pp = phase4 + (size_t)(D-1)*1024 + lane*16;
    #pragma unroll
    for (int r = 0; r < 16; ++r) phv[r] = pp[r];
  }
  rx_gate<D,0>(re, im, gcT, lane);
  rx_gate<D,1>(re, im, gcT, lane);
  rx_gate<D,2>(re, im, gcT, lane);
  rx_gate<D,3>(re, im, gcT, lane);
  rx_gate<D,4>(re, im, gcT, lane);
  rx_gate<D,5>(re, im, gcT, lane);
  rx_gate<D,6>(re, im, gcT, lane);
  rx_gate<D,7>(re, im, gcT, lane);
  rx_gate<D,8>(re, im, gcT, lane);
  rx_gate<D,9>(re, im, gcT, lane);
  if constexpr (D <= 4){
    #pragma unroll
    for (int r = 0; r < 16; ++r){
      float4 ph = phv[r];
      f32x2 cp = {ph.x, ph.y};
      f32x2 sp = {ph.z, ph.w};
      f32x2 ar = re[r], ai = im[r];
      re[r] = fma2(-sp, ai, cp*ar);
      im[r] = fma2( sp, ar, cp*ai);
    }
  }
}

// ---- K2: one wave per TWO samples (R11 measured-best structure) ----
__global__ __launch_bounds__(256) void k2_qsim(
    const float* __restrict__ enc, const unsigned* __restrict__ gkey,
    const float4* __restrict__ U0, const float* __restrict__ gcT,
    const float4* __restrict__ phase4,
    const float* __restrict__ fcWs, const float* __restrict__ fcB,
    float* __restrict__ outB)
{
  int tid  = threadIdx.x;
  int lane = tid & 63;
  int wid  = tid >> 6;
  int sA   = blockIdx.x * 8 + wid * 2;
  int sB   = sA + 1;

  float invr = 3.14159265358979f / (funkey(*gkey) + 1e-8f);

  f32x2 lr, li;
  {
    #pragma unroll
    for (int j = 0; j < 5; ++j){
      int q = (j < 4) ? (5 + j) : 9;
      float angA = enc[(size_t)sA*NQ + q] * invr;
      float angB = enc[(size_t)sB*NQ + q] * invr;
      f32x2 cv = {__cosf(angA), __cosf(angB)};
      f32x2 sv = {__sinf(angA), __sinf(angB)};
      float4 a = U0[q*2+0], b = U0[q*2+1];
      f32x2 pa_r = fma2(bc(a.z), sv, bc(a.x)*cv);
      f32x2 pa_i = fma2(bc(a.w), sv, bc(a.y)*cv);
      f32x2 pb_r = fma2(bc(b.z), sv, bc(b.x)*cv);
      f32x2 pb_i = fma2(bc(b.w), sv, bc(b.y)*cv);
      bool bit = (lane >> j) & 1;
      f32x2 fr = bit ? pb_r : pa_r;
      f32x2 fi = bit ? pb_i : pa_i;
      if (j == 0){ lr = fr; li = fi; }
      else {
        f32x2 t = lr*fr - li*fi;
        li = fma2(lr, fi, li*fr);
        lr = t;
      }
    }
  }

  f32x2 A0r, A0i, A1r, A1i;
  {
    float angA = enc[(size_t)sA*NQ + 4] * invr;
    float angB = enc[(size_t)sB*NQ + 4] * invr;
    f32x2 cv = {__cosf(angA), __cosf(angB)};
    f32x2 sv = {__sinf(angA), __sinf(angB)};
    float4 a = U0[8], b = U0[9];
    f32x2 pa_r = fma2(bc(a.z), sv, bc(a.x)*cv);
    f32x2 pa_i = fma2(bc(a.w), sv, bc(a.y)*cv);
    f32x2 pb_r = fma2(bc(b.z), sv, bc(b.x)*cv);
    f32x2 pb_i = fma2(bc(b.w), sv, bc(b.y)*cv);
    bool e = __popc(lane) & 1;
    A0r = e ? pb_r : pa_r;  A0i = e ? pb_i : pa_i;
    A1r = e ? pa_r : pb_r;  A1i = e ? pa_i : pb_i;
  }

  f32x2 re[16], im[16];
  re[0] = lr; im[0] = li;
  #pragma unroll
  for (int k = 0; k < 4; ++k){
    float angA = enc[(size_t)sA*NQ + k] * invr;
    float angB = enc[(size_t)sB*NQ + k] * invr;
    f32x2 cv = {__cosf(angA), __cosf(angB)};
    f32x2 sv = {__sinf(angA), __sinf(angB)};
    float4 a = U0[k*2+0], b = U0[k*2+1];
    f32x2 pa_r = fma2(bc(a.z), sv, bc(a.x)*cv);
    f32x2 pa_i = fma2(bc(a.w), sv, bc(a.y)*cv);
    f32x2 pb_r = fma2(bc(b.z), sv, bc(b.x)*cv);
    f32x2 pb_i = fma2(bc(b.w), sv, bc(b.y)*cv);
    int w = 1 << k;
    #pragma unroll
    for (int r = 0; r < 8; ++r) if (r < w){
      f32x2 xr = re[r], xi = im[r];
      re[r|w] = xr*pb_r - xi*pb_i;
      im[r|w] = fma2(xr, pb_i, xi*pb_r);
      re[r]   = xr*pa_r - xi*pa_i;
      im[r]   = fma2(xr, pa_i, xi*pa_r);
    }
  }
  #pragma unroll
  for (int r = 0; r < 16; ++r){
    f32x2 sr = (__builtin_popcount(r) & 1) ? A1r : A0r;
    f32x2 si = (__builtin_popcount(r) & 1) ? A1i : A0i;
    f32x2 xr = re[r], xi = im[r];
    re[r] = xr*sr - xi*si;
    im[r] = fma2(xr, si, xi*sr);
  }

  run_layer<1>(re, im, gcT, phase4, lane);
  run_layer<2>(re, im, gcT, phase4, lane);
  run_layer<3>(re, im, gcT, phase4, lane);
  run_layer<4>(re, im, gcT, phase4, lane);
  run_layer<5>(re, im, gcT, phase4, lane);

  f32x2 p2[16];
  #pragma unroll
  for (int r = 0; r < 16; ++r) p2[r] = fma2(re[r], re[r], im[r]*im[r]);
  #pragma unroll
  for (int k = 0; k < 4; ++k){
    int w = 1 << k;
    #pragma unroll
    for (int r = 0; r < 16; ++r) if (!(r & w)){
      f32x2 a = p2[r], b = p2[r|w];
      p2[r] = a + b; p2[r|w] = a - b;
    }
  }
  f32x2 o2[4] = {{0.f,0.f},{0.f,0.f},{0.f,0.f},{0.f,0.f}};
  #pragma unroll
  for (int q = 0; q < NQ; ++q){
    constexpr int RALL[NQ] = {FT(TAB.meas[0]),FT(TAB.meas[1]),FT(TAB.meas[2]),
                              FT(TAB.meas[3]),FT(TAB.meas[4]),FT(TAB.meas[5]),
                              FT(TAB.meas[6]),FT(TAB.meas[7]),FT(TAB.meas[8]),
                              FT(TAB.meas[9])};
    int R = RALL[q];
    f32x2 tq = p2[R & 15];
    unsigned sg = (unsigned)(__popc((R >> 4) & lane) << 31);
    tq.x = __uint_as_float(__float_as_uint(tq.x) ^ sg);
    tq.y = __uint_as_float(__float_as_uint(tq.y) ^ sg);
    #pragma unroll
    for (int j = 0; j < 4; ++j) o2[j] = fma2(tq, bc(fcWs[j*NQ + q]), o2[j]);
  }
  // butterfly reduce: steps 1..8 on DPP (VALU), 16/32 via shfl (DS)
  #pragma unroll
  for (int j = 0; j < 4; ++j){
    o2[j].x += lxs<1>(o2[j].x);   o2[j].y += lxs<1>(o2[j].y);
    o2[j].x += lxs<2>(o2[j].x);   o2[j].y += lxs<2>(o2[j].y);
    o2[j].x += lxs<4>(o2[j].x);   o2[j].y += lxs<4>(o2[j].y);
    o2[j].x += lxs<8>(o2[j].x);   o2[j].y += lxs<8>(o2[j].y);
    o2[j].x += __shfl_xor(o2[j].x, 16, 64);
    o2[j].y += __shfl_xor(o2[j].y, 16, 64);
    o2[j].x += __shfl_xor(o2[j].x, 32, 64);
    o2[j].y += __shfl_xor(o2[j].y, 32, 64);
  }
  if (lane == 0){
    float4 a4 = make_float4(o2[0].x+fcB[0], o2[1].x+fcB[1], o2[2].x+fcB[2], o2[3].x+fcB[3]);
    float4 b4 = make_float4(o2[0].y+fcB[0], o2[1].y+fcB[1], o2[2].y+fcB[2], o2[3].y+fcB[3]);
    *reinterpret_cast<float4*>(&outB[(size_t)sA*4]) = a4;
    *reinterpret_cast<float4*>(&outB[(size_t)sB*4]) = b4;
  }
}

// ---- K34: fused deterministic BN stats + apply (single block) ----
__global__ __launch_bounds__(1024) void k34_stats_bn(const float* __restrict__ outB,
    const float* __restrict__ gamma, const float* __restrict__ beta,
    float* __restrict__ out)
{
  __shared__ float ls[16][8];
  __shared__ float sstat[8];
  int tid = threadIdx.x;
  float sum[4] = {0,0,0,0}, sq[4] = {0,0,0,0};
  for (int row = tid; row < B_SZ; row += 1024){
    float4 v = *reinterpret_cast<const float4*>(outB + (size_t)row*4);
    sum[0]+=v.x; sq[0]+=v.x*v.x;
    sum[1]+=v.y; sq[1]+=v.y*v.y;
    sum[2]+=v.z; sq[2]+=v.z*v.z;
    sum[3]+=v.w; sq[3]+=v.w*v.w;
  }
  #pragma unroll
  for (int k = 0; k < 4; ++k){
    #pragma unroll
    for (int st = 1; st < 64; st <<= 1){
      sum[k] += __shfl_xor(sum[k], st, 64);
      sq[k]  += __shfl_xor(sq[k],  st, 64);
    }
  }
  int lane = tid & 63, w = tid >> 6;
  if (lane == 0){
    #pragma unroll
    for (int k = 0; k < 4; ++k){ ls[w][k] = sum[k]; ls[w][4+k] = sq[k]; }
  }
  __syncthreads();
  if (tid == 0){
    float fs[8];
    #pragma unroll
    for (int k = 0; k < 8; ++k){
      float a = 0.f;
      for (int w2 = 0; w2 < 16; ++w2) a += ls[w2][k];
      fs[k] = a;
    }
    #pragma unroll
    for (int k = 0; k < 4; ++k){
      float mean = fs[k] * (1.f/B_SZ);
      float var  = fs[4+k] * (1.f/B_SZ) - mean*mean;
      sstat[k]   = mean;
      sstat[4+k] = rsqrtf(var + 1e-5f);
    }
  }
  __syncthreads();
  float m0 = sstat[0], m1 = sstat[1], m2 = sstat[2], m3 = sstat[3];
  float r0 = sstat[4], r1 = sstat[5], r2 = sstat[6], r3 = sstat[7];
  float g0 = gamma[0], g1 = gamma[1], g2 = gamma[2], g3 = gamma[3];
  float b0 = beta[0],  b1 = beta[1],  b2 = beta[2],  b3 = beta[3];
  for (int row = tid; row < B_SZ; row += 1024){
    float4 v = *reinterpret_cast<const float4*>(outB + (size_t)row*4);
    v.x = fmaf(g0*(v.x - m0), r0, b0);
    v.y = fmaf(g1*(v.y - m1), r1, b1);
    v.z = fmaf(g2*(v.z - m2), r2, b2);
    v.w = fmaf(g3*(v.w - m3), r3, b3);
    *reinterpret_cast<float4*>(out + (size_t)row*4) = v;
  }
}

extern "C" void kernel_launch(void* const* d_in, const int* in_sizes, int n_in,
                              void* d_out, int out_size, void* d_ws, size_t ws_size,
                              hipStream_t stream)
{
  const float* x     = (const float*)d_in[0];
  const float* encW  = (const float*)d_in[1];
  const float* encB  = (const float*)d_in[2];
  const float* wts   = (const float*)d_in[3];
  const float* fcW   = (const float*)d_in[4];
  const float* fcB   = (const float*)d_in[5];
  const float* gamma = (const float*)d_in[6];
  const float* beta  = (const float*)d_in[7];

  char* ws = (char*)d_ws;
  unsigned* gkey  = (unsigned*)ws;                      // 4 B
  float4*  U0     = (float4*)(ws + 256);                // 320 B
  float*   gcT    = (float*)(ws + 1024);                // 200 B
  float*   fcWs   = (float*)(ws + 2048);                // 160 B
  float4*  phase  = (float4*)(ws + 4096);               // 64 KB (c,c,s,s)
  float*   enc    = (float*)(ws + 4096 + 65536);
  float*   outB   = (float*)(ws + 4096 + 65536 + (size_t)B_SZ*NQ*4);

  hipLaunchKernelGGL(k_prep, dim3(16), dim3(256), 0, stream, wts, fcW, U0, gcT, phase, fcWs, gkey);
  hipLaunchKernelGGL(k1_encode, dim3(B_SZ/16), dim3(256), 0, stream,
                     x, encW, encB, enc, gkey);
  hipLaunchKernelGGL(k2_qsim, dim3(B_SZ/8), dim3(256), 0, stream,
                     enc, gkey, U0, gcT, phase, fcWs, fcB, outB);
  hipLaunchKernelGGL(k34_stats_bn, dim3(1), dim3(1024), 0, stream,
                     outB, gamma, beta, (float*)d_out);
}

// Round 14
// 159.105 us; speedup vs baseline: 1.1225x; 1.0924x over previous
//
#include <hip/hip_runtime.h>
#include <math.h>

#define B_SZ 16384
#define NQ 10
#define DEPTH 6

typedef float f32x2 __attribute__((ext_vector_type(2)));

__device__ __forceinline__ f32x2 bc(float x){ return (f32x2){x, x}; }
__device__ __forceinline__ f32x2 fma2(f32x2 a, f32x2 b, f32x2 c){
  return __builtin_elementwise_fma(a, b, c);
}

// ---- constexpr GF(2) tracking of the CNOT ring (sequential, matches ref) ----
struct Tables {
  int m[DEPTH][NQ];
  int R[DEPTH][NQ];
  int meas[NQ];
};
constexpr Tables make_tables(){
  Tables t{};
  int cols[NQ] = {}, rows[NQ] = {};
  for (int i = 0; i < NQ; ++i){ cols[i] = 1 << i; rows[i] = 1 << i; }
  for (int d = 0; d < DEPTH; ++d){
    for (int q = 0; q < NQ; ++q){ t.m[d][q] = cols[q]; t.R[d][q] = rows[q]; }
    for (int c = 0; c < NQ; ++c){
      int tt = (c + 1) % NQ;
      cols[c]  ^= cols[tt];
      rows[tt] ^= rows[c];
    }
  }
  for (int q = 0; q < NQ; ++q) t.meas[q] = rows[q];
  return t;
}
constexpr Tables TAB = make_tables();

// ---- storage-basis change Phi (R9, proven) ----
constexpr int SM(int m){
  return (m & 0xF) | (((m >> 5) & 0xF) << 4) | (((m >> 9) & 1) << 8)
       | ((__builtin_popcount(m) & 1) << 9);
}
constexpr int FT(int F){
  int a4  = (F >> 4) & 1;
  int lo  = (F & 0xF)        ^ (a4 ? 0xF : 0);
  int mid = ((F >> 5) & 0xF) ^ (a4 ? 0xF : 0);
  int b8  = ((F >> 9) & 1) ^ a4;
  return lo | (mid << 4) | (b8 << 8) | (a4 << 9);
}

// ---- monotone float<->uint key for atomicMax over signed floats ----
__device__ __forceinline__ unsigned fkey(float x){
  unsigned b = __float_as_uint(x);
  return (b & 0x80000000u) ? ~b : (b | 0x80000000u);
}
__device__ __forceinline__ float funkey(unsigned k){
  unsigned b = (k & 0x80000000u) ? (k ^ 0x80000000u) : ~k;
  return __uint_as_float(b);
}

// ======== lane-xor machinery: DPP for masks 1..15, ds_bpermute otherwise ====
constexpr int quadctl(int m){ return (0^m) | ((1^m)<<2) | ((2^m)<<4) | ((3^m)<<6); }

template<int CTRL>
__device__ __forceinline__ float dppf(float x){
  return __uint_as_float((unsigned)__builtin_amdgcn_update_dpp(
      0, (int)__float_as_uint(x), CTRL, 0xF, 0xF, true));
}
template<int LM>   // 1..15 only
__device__ __forceinline__ float lxs(float x){
  if constexpr (LM == 0){
    return x;
  } else if constexpr (LM <= 3){
    return dppf<quadctl(LM)>(x);
  } else if constexpr (LM == 7){
    return dppf<0x141>(x);
  } else if constexpr (LM == 8){
    return dppf<0x128>(x);
  } else if constexpr (LM == 15){
    return dppf<0x140>(x);
  } else if constexpr ((LM & 12) == 4){
    return lxs<LM ^ 7>(dppf<0x141>(x));
  } else if constexpr ((LM & 12) == 8){
    return lxs<LM ^ 8>(dppf<0x128>(x));
  } else {
    return lxs<LM ^ 15>(dppf<0x140>(x));
  }
}
template<int LM>
__device__ __forceinline__ f32x2 lx2(f32x2 v){
  f32x2 r;
  r.x = lxs<LM>(v.x);
  r.y = lxs<LM>(v.y);
  return r;
}
__device__ __forceinline__ f32x2 lxd2(int adr, f32x2 v){
  f32x2 r;
  r.x = __uint_as_float((unsigned)__builtin_amdgcn_ds_bpermute(adr, (int)__float_as_uint(v.x)));
  r.y = __uint_as_float((unsigned)__builtin_amdgcn_ds_bpermute(adr, (int)__float_as_uint(v.y)));
  return r;
}

// ---- prep ----
__global__ __launch_bounds__(256) void k_prep(const float* __restrict__ wts,
    const float* __restrict__ fcW,
    float4* __restrict__ U0,     // 20
    float* __restrict__ gcT,     // 50: tan(ax)
    float4* __restrict__ phase,  // 4*1024: (c,c,s,s) per storage index
    float* __restrict__ fcWs,    // 40: fcW * (prod cos)^2
    unsigned* __restrict__ gkey)
{
  int idx = blockIdx.x * 256 + threadIdx.x;
  if (idx < 4096){
    int layer = 1 + (idx >> 10);
    int p = idx & 1023;          // STORAGE index
    float phi = 0.f;
    for (int q = 0; q < NQ; ++q){
      float az = wts[(layer*NQ + q)*2 + 1] * 0.5f;
      int Fs = FT(TAB.R[layer][q]);
      phi += (__popc(Fs & p) & 1) ? az : -az;
    }
    float c = cosf(phi), s = sinf(phi);
    phase[idx] = make_float4(c, c, s, s);
  }
  if (blockIdx.x == 0){
    int t = threadIdx.x;
    if (t < NQ){
      float ax = wts[t*2+0]*0.5f, az = wts[t*2+1]*0.5f;
      float ca=cosf(ax), sa=sinf(ax), cz=cosf(az), sz=sinf(az);
      U0[t*2+0] = make_float4(ca*cz, -ca*sz, -sa*sz, -sa*cz);
      U0[t*2+1] = make_float4(sa*sz, -sa*cz,  ca*cz,  ca*sz);
    } else if (t >= 64 && t < 64 + 50){
      int g = t - 64;
      int d = 1 + g/10, q = g % 10;
      float ax = wts[(d*NQ+q)*2+0]*0.5f;
      gcT[g] = tanf(ax);
    } else if (t == 120){
      *gkey = 0u;
    } else if (t == 121){
      float pc = 1.f;
      for (int g = 0; g < 50; ++g){
        int d = 1 + g/10, q = g % 10;
        pc *= cosf(wts[(d*NQ+q)*2+0]*0.5f);
      }
      float s2 = pc * pc;
      for (int j = 0; j < 40; ++j) fcWs[j] = fcW[j] * s2;
    }
  }
}

// ---- K1: coalesced LDS-staged pool -> encode -> global max (R10, proven) ----
__global__ __launch_bounds__(256) void k1_encode(const float* __restrict__ x,
    const float* __restrict__ encW, const float* __restrict__ encB,
    float* __restrict__ encOut, unsigned* __restrict__ gkey)
{
  __shared__ float lds[4][788];
  __shared__ float poolS[4][16];
  __shared__ float wmax[4];
  int tid = threadIdx.x, lane = tid & 63, wid = tid >> 6;
  float bm = -INFINITY;

  #pragma unroll 1
  for (int it = 0; it < 4; ++it){
    int s = blockIdx.x * 16 + it * 4 + wid;
    const float4* xs4 = reinterpret_cast<const float4*>(x + (size_t)s * 784);
    float4* l4 = reinterpret_cast<float4*>(lds[wid]);
    l4[lane]       = xs4[lane];
    l4[lane + 64]  = xs4[lane + 64];
    l4[lane + 128] = xs4[lane + 128];
    if (lane < 4) l4[lane + 192] = xs4[lane + 192];
    __syncthreads();
    int b = lane & 15, sub = lane >> 4;
    int r0 = (b >> 2) * 6, c0 = (b & 3) * 6;
    float acc = 0.f;
    #pragma unroll
    for (int k = 0; k < 9; ++k){
      int e = sub * 9 + k;
      acc += lds[wid][(r0 + e / 6) * 28 + c0 + e % 6];
    }
    acc += __shfl_xor(acc, 16, 64);
    acc += __shfl_xor(acc, 32, 64);
    if (lane < 16) poolS[wid][lane] = acc * (1.f/36.f);
    __syncthreads();
    float ev = -INFINITY;
    if (lane < NQ){
      float e = encB[lane];
      #pragma unroll
      for (int k = 0; k < 16; ++k) e = fmaf(poolS[wid][k], encW[lane*16+k], e);
      encOut[(size_t)s*NQ + lane] = e;
      ev = e;
    }
    #pragma unroll
    for (int st = 1; st < 16; st <<= 1) ev = fmaxf(ev, __shfl_xor(ev, st, 64));
    bm = fmaxf(bm, ev);
  }
  if (lane == 0) wmax[wid] = bm;
  __syncthreads();
  if (tid == 0){
    float mm = fmaxf(fmaxf(wmax[0], wmax[1]), fmaxf(wmax[2], wmax[3]));
    atomicMax(gkey, fkey(mm));
  }
}

// ---- Rx gate, tangent form, storage basis (R9 tiers — measured best) ----
template<int D, int Q>
__device__ __forceinline__ void rx_gate(f32x2 (&re)[16], f32x2 (&im)[16],
    const float* __restrict__ gcT, int lane)
{
  constexpr int ms = SM(TAB.m[D][Q]);
  constexpr int rm = ms & 15;
  constexpr int lm = (ms >> 4) & 63;
  float Tt = gcT[(D-1)*NQ + Q];
  f32x2 T = bc(Tt), nT = bc(-Tt);

  if constexpr (lm == 0){
    constexpr int lb = rm & (-rm);
    #pragma unroll
    for (int r = 0; r < 16; ++r) if (!(r & lb)){
      int r2 = r ^ rm;
      f32x2 ar = re[r],  ai = im[r];
      f32x2 br = re[r2], bi = im[r2];
      re[r]  = fma2(T,  bi, ar);
      im[r]  = fma2(nT, br, ai);
      re[r2] = fma2(T,  ai, br);
      im[r2] = fma2(nT, ar, bi);
    }
  } else if constexpr (lm < 16){
    if constexpr (rm == 0){
      #pragma unroll
      for (int r = 0; r < 16; ++r){
        f32x2 bi = lx2<lm>(im[r]);
        f32x2 br = lx2<lm>(re[r]);
        re[r] = fma2(T,  bi, re[r]);
        im[r] = fma2(nT, br, im[r]);
      }
    } else {
      constexpr int lb = rm & (-rm);
      #pragma unroll
      for (int r = 0; r < 16; ++r) if (!(r & lb)){
        int r2 = r ^ rm;
        f32x2 bi2 = lx2<lm>(im[r2]);
        f32x2 br2 = lx2<lm>(re[r2]);
        f32x2 bi1 = lx2<lm>(im[r]);
        f32x2 br1 = lx2<lm>(re[r]);
        re[r]  = fma2(T,  bi2, re[r]);
        im[r]  = fma2(nT, br2, im[r]);
        re[r2] = fma2(T,  bi1, re[r2]);
        im[r2] = fma2(nT, br1, im[r2]);
      }
    }
  } else {
    const int adr = (lane ^ lm) << 2;
    if constexpr (rm == 0){
      #pragma unroll
      for (int r = 0; r < 16; ++r){
        f32x2 bi = lxd2(adr, im[r]);
        f32x2 br = lxd2(adr, re[r]);
        re[r] = fma2(T,  bi, re[r]);
        im[r] = fma2(nT, br, im[r]);
      }
    } else {
      constexpr int lb = rm & (-rm);
      #pragma unroll
      for (int r = 0; r < 16; ++r) if (!(r & lb)){
        int r2 = r ^ rm;
        f32x2 bi2 = lxd2(adr, im[r2]);
        f32x2 br2 = lxd2(adr, re[r2]);
        f32x2 bi1 = lxd2(adr, im[r]);
        f32x2 br1 = lxd2(adr, re[r]);
        re[r]  = fma2(T,  bi2, re[r]);
        im[r]  = fma2(nT, br2, im[r]);
        re[r2] = fma2(T,  bi1, re[r2]);
        im[r2] = fma2(nT, br1, im[r2]);
      }
    }
  }
}

template<int D>
__device__ __forceinline__ void run_layer(f32x2 (&re)[16], f32x2 (&im)[16],
    const float* __restrict__ gcT, const float4* __restrict__ phase4, int lane)
{
  float4 phv[16];
  if constexpr (D <= 4){
    const float4* __restrict__ pp = phase4 + (size_t)(D-1)*1024 + lane*16;
    #pragma unroll
    for (int r = 0; r < 16; ++r) phv[r] = pp[r];
  }
  rx_gate<D,0>(re, im, gcT, lane);
  rx_gate<D,1>(re, im, gcT, lane);
  rx_gate<D,2>(re, im, gcT, lane);
  rx_gate<D,3>(re, im, gcT, lane);
  rx_gate<D,4>(re, im, gcT, lane);
  rx_gate<D,5>(re, im, gcT, lane);
  rx_gate<D,6>(re, im, gcT, lane);
  rx_gate<D,7>(re, im, gcT, lane);
  rx_gate<D,8>(re, im, gcT, lane);
  rx_gate<D,9>(re, im, gcT, lane);
  if constexpr (D <= 4){
    #pragma unroll
    for (int r = 0; r < 16; ++r){
      float4 ph = phv[r];
      f32x2 cp = {ph.x, ph.y};
      f32x2 sp = {ph.z, ph.w};
      f32x2 ar = re[r], ai = im[r];
      re[r] = fma2(-sp, ai, cp*ar);
      im[r] = fma2( sp, ar, cp*ai);
    }
  }
}

// ---- K2: one wave per TWO samples (R11/R13 measured-best structure) ----
__global__ __launch_bounds__(256) void k2_qsim(
    const float* __restrict__ enc, const unsigned* __restrict__ gkey,
    const float4* __restrict__ U0, const float* __restrict__ gcT,
    const float4* __restrict__ phase4,
    const float* __restrict__ fcWs, const float* __restrict__ fcB,
    float* __restrict__ outB)
{
  int tid  = threadIdx.x;
  int lane = tid & 63;
  int wid  = tid >> 6;
  int sA   = blockIdx.x * 8 + wid * 2;
  int sB   = sA + 1;

  float invr = 3.14159265358979f / (funkey(*gkey) + 1e-8f);

  f32x2 lr, li;
  {
    #pragma unroll
    for (int j = 0; j < 5; ++j){
      int q = (j < 4) ? (5 + j) : 9;
      float angA = enc[(size_t)sA*NQ + q] * invr;
      float angB = enc[(size_t)sB*NQ + q] * invr;
      f32x2 cv = {__cosf(angA), __cosf(angB)};
      f32x2 sv = {__sinf(angA), __sinf(angB)};
      float4 a = U0[q*2+0], b = U0[q*2+1];
      f32x2 pa_r = fma2(bc(a.z), sv, bc(a.x)*cv);
      f32x2 pa_i = fma2(bc(a.w), sv, bc(a.y)*cv);
      f32x2 pb_r = fma2(bc(b.z), sv, bc(b.x)*cv);
      f32x2 pb_i = fma2(bc(b.w), sv, bc(b.y)*cv);
      bool bit = (lane >> j) & 1;
      f32x2 fr = bit ? pb_r : pa_r;
      f32x2 fi = bit ? pb_i : pa_i;
      if (j == 0){ lr = fr; li = fi; }
      else {
        f32x2 t = lr*fr - li*fi;
        li = fma2(lr, fi, li*fr);
        lr = t;
      }
    }
  }

  f32x2 A0r, A0i, A1r, A1i;
  {
    float angA = enc[(size_t)sA*NQ + 4] * invr;
    float angB = enc[(size_t)sB*NQ + 4] * invr;
    f32x2 cv = {__cosf(angA), __cosf(angB)};
    f32x2 sv = {__sinf(angA), __sinf(angB)};
    float4 a = U0[8], b = U0[9];
    f32x2 pa_r = fma2(bc(a.z), sv, bc(a.x)*cv);
    f32x2 pa_i = fma2(bc(a.w), sv, bc(a.y)*cv);
    f32x2 pb_r = fma2(bc(b.z), sv, bc(b.x)*cv);
    f32x2 pb_i = fma2(bc(b.w), sv, bc(b.y)*cv);
    bool e = __popc(lane) & 1;
    A0r = e ? pb_r : pa_r;  A0i = e ? pb_i : pa_i;
    A1r = e ? pa_r : pb_r;  A1i = e ? pa_i : pb_i;
  }

  f32x2 re[16], im[16];
  re[0] = lr; im[0] = li;
  #pragma unroll
  for (int k = 0; k < 4; ++k){
    float angA = enc[(size_t)sA*NQ + k] * invr;
    float angB = enc[(size_t)sB*NQ + k] * invr;
    f32x2 cv = {__cosf(angA), __cosf(angB)};
    f32x2 sv = {__sinf(angA), __sinf(angB)};
    float4 a = U0[k*2+0], b = U0[k*2+1];
    f32x2 pa_r = fma2(bc(a.z), sv, bc(a.x)*cv);
    f32x2 pa_i = fma2(bc(a.w), sv, bc(a.y)*cv);
    f32x2 pb_r = fma2(bc(b.z), sv, bc(b.x)*cv);
    f32x2 pb_i = fma2(bc(b.w), sv, bc(b.y)*cv);
    int w = 1 << k;
    #pragma unroll
    for (int r = 0; r < 8; ++r) if (r < w){
      f32x2 xr = re[r], xi = im[r];
      re[r|w] = xr*pb_r - xi*pb_i;
      im[r|w] = fma2(xr, pb_i, xi*pb_r);
      re[r]   = xr*pa_r - xi*pa_i;
      im[r]   = fma2(xr, pa_i, xi*pa_r);
    }
  }
  #pragma unroll
  for (int r = 0; r < 16; ++r){
    f32x2 sr = (__builtin_popcount(r) & 1) ? A1r : A0r;
    f32x2 si = (__builtin_popcount(r) & 1) ? A1i : A0i;
    f32x2 xr = re[r], xi = im[r];
    re[r] = xr*sr - xi*si;
    im[r] = fma2(xr, si, xi*sr);
  }

  run_layer<1>(re, im, gcT, phase4, lane);
  run_layer<2>(re, im, gcT, phase4, lane);
  run_layer<3>(re, im, gcT, phase4, lane);
  run_layer<4>(re, im, gcT, phase4, lane);
  run_layer<5>(re, im, gcT, phase4, lane);

  f32x2 p2[16];
  #pragma unroll
  for (int r = 0; r < 16; ++r) p2[r] = fma2(re[r], re[r], im[r]*im[r]);
  #pragma unroll
  for (int k = 0; k < 4; ++k){
    int w = 1 << k;
    #pragma unroll
    for (int r = 0; r < 16; ++r) if (!(r & w)){
      f32x2 a = p2[r], b = p2[r|w];
      p2[r] = a + b; p2[r|w] = a - b;
    }
  }
  f32x2 o2[4] = {{0.f,0.f},{0.f,0.f},{0.f,0.f},{0.f,0.f}};
  #pragma unroll
  for (int q = 0; q < NQ; ++q){
    constexpr int RALL[NQ] = {FT(TAB.meas[0]),FT(TAB.meas[1]),FT(TAB.meas[2]),
                              FT(TAB.meas[3]),FT(TAB.meas[4]),FT(TAB.meas[5]),
                              FT(TAB.meas[6]),FT(TAB.meas[7]),FT(TAB.meas[8]),
                              FT(TAB.meas[9])};
    int R = RALL[q];
    f32x2 tq = p2[R & 15];
    unsigned sg = (unsigned)(__popc((R >> 4) & lane) << 31);
    tq.x = __uint_as_float(__float_as_uint(tq.x) ^ sg);
    tq.y = __uint_as_float(__float_as_uint(tq.y) ^ sg);
    #pragma unroll
    for (int j = 0; j < 4; ++j) o2[j] = fma2(tq, bc(fcWs[j*NQ + q]), o2[j]);
  }
  // butterfly reduce: steps 1..8 on DPP (VALU), 16/32 via shfl (DS)
  #pragma unroll
  for (int j = 0; j < 4; ++j){
    o2[j].x += lxs<1>(o2[j].x);   o2[j].y += lxs<1>(o2[j].y);
    o2[j].x += lxs<2>(o2[j].x);   o2[j].y += lxs<2>(o2[j].y);
    o2[j].x += lxs<4>(o2[j].x);   o2[j].y += lxs<4>(o2[j].y);
    o2[j].x += lxs<8>(o2[j].x);   o2[j].y += lxs<8>(o2[j].y);
    o2[j].x += __shfl_xor(o2[j].x, 16, 64);
    o2[j].y += __shfl_xor(o2[j].y, 16, 64);
    o2[j].x += __shfl_xor(o2[j].x, 32, 64);
    o2[j].y += __shfl_xor(o2[j].y, 32, 64);
  }
  if (lane == 0){
    float4 a4 = make_float4(o2[0].x+fcB[0], o2[1].x+fcB[1], o2[2].x+fcB[2], o2[3].x+fcB[3]);
    float4 b4 = make_float4(o2[0].y+fcB[0], o2[1].y+fcB[1], o2[2].y+fcB[2], o2[3].y+fcB[3]);
    *reinterpret_cast<float4*>(&outB[(size_t)sA*4]) = a4;
    *reinterpret_cast<float4*>(&outB[(size_t)sB*4]) = b4;
  }
}

// ---- K3: deterministic BN stats (single block) ----
__global__ __launch_bounds__(1024) void k3_stats(const float* __restrict__ outB,
                                                 float* __restrict__ stats)
{
  int tid = threadIdx.x;
  float sum[4] = {0,0,0,0}, sq[4] = {0,0,0,0};
  for (int row = tid; row < B_SZ; row += 1024){
    float4 v = *reinterpret_cast<const float4*>(outB + (size_t)row*4);
    sum[0]+=v.x; sq[0]+=v.x*v.x;
    sum[1]+=v.y; sq[1]+=v.y*v.y;
    sum[2]+=v.z; sq[2]+=v.z*v.z;
    sum[3]+=v.w; sq[3]+=v.w*v.w;
  }
  #pragma unroll
  for (int k = 0; k < 4; ++k){
    #pragma unroll
    for (int st = 1; st < 64; st <<= 1){
      sum[k] += __shfl_xor(sum[k], st, 64);
      sq[k]  += __shfl_xor(sq[k],  st, 64);
    }
  }
  __shared__ float ls[16][8];
  int lane = tid & 63, w = tid >> 6;
  if (lane == 0){
    #pragma unroll
    for (int k = 0; k < 4; ++k){ ls[w][k] = sum[k]; ls[w][4+k] = sq[k]; }
  }
  __syncthreads();
  if (tid == 0){
    float fs[8];
    #pragma unroll
    for (int k = 0; k < 8; ++k){
      float a = 0.f;
      for (int w2 = 0; w2 < 16; ++w2) a += ls[w2][k];
      fs[k] = a;
    }
    #pragma unroll
    for (int k = 0; k < 4; ++k){
      float mean = fs[k] * (1.f/B_SZ);
      float var  = fs[4+k] * (1.f/B_SZ) - mean*mean;
      stats[k]   = mean;
      stats[4+k] = rsqrtf(var + 1e-5f);
    }
  }
}

// ---- K4: apply BN (parallel, 256 blocks) ----
__global__ __launch_bounds__(256) void k4_bn(const float* __restrict__ outB,
    const float* __restrict__ stats, const float* __restrict__ gamma,
    const float* __restrict__ beta, float* __restrict__ out)
{
  int idx = blockIdx.x * 256 + threadIdx.x;
  int c = idx & 3;
  float v = outB[idx];
  out[idx] = gamma[c] * (v - stats[c]) * stats[4+c] + beta[c];
}

extern "C" void kernel_launch(void* const* d_in, const int* in_sizes, int n_in,
                              void* d_out, int out_size, void* d_ws, size_t ws_size,
                              hipStream_t stream)
{
  const float* x     = (const float*)d_in[0];
  const float* encW  = (const float*)d_in[1];
  const float* encB  = (const float*)d_in[2];
  const float* wts   = (const float*)d_in[3];
  const float* fcW   = (const float*)d_in[4];
  const float* fcB   = (const float*)d_in[5];
  const float* gamma = (const float*)d_in[6];
  const float* beta  = (const float*)d_in[7];

  char* ws = (char*)d_ws;
  unsigned* gkey  = (unsigned*)ws;                      // 4 B
  float4*  U0     = (float4*)(ws + 256);                // 320 B
  float*   gcT    = (float*)(ws + 1024);                // 200 B
  float*   fcWs   = (float*)(ws + 2048);                // 160 B
  float4*  phase  = (float4*)(ws + 4096);               // 64 KB (c,c,s,s)
  float*   enc    = (float*)(ws + 4096 + 65536);
  float*   outB   = (float*)(ws + 4096 + 65536 + (size_t)B_SZ*NQ*4);
  float*   stats  = (float*)(ws + 4096 + 65536 + (size_t)B_SZ*NQ*4 + (size_t)B_SZ*4*4);

  hipLaunchKernelGGL(k_prep, dim3(16), dim3(256), 0, stream, wts, fcW, U0, gcT, phase, fcWs, gkey);
  hipLaunchKernelGGL(k1_encode, dim3(B_SZ/16), dim3(256), 0, stream,
                     x, encW, encB, enc, gkey);
  hipLaunchKernelGGL(k2_qsim, dim3(B_SZ/8), dim3(256), 0, stream,
                     enc, gkey, U0, gcT, phase, fcWs, fcB, outB);
  hipLaunchKernelGGL(k3_stats, dim3(1), dim3(1024), 0, stream, outB, stats);
  hipLaunchKernelGGL(k4_bn, dim3(B_SZ*4/256), dim3(256), 0, stream,
                     outB, stats, gamma, beta, (float*)d_out);
}

// Round 15
// 143.144 us; speedup vs baseline: 1.2476x; 1.1115x over previous
//
#include <hip/hip_runtime.h>
#include <math.h>

#define B_SZ 16384
#define NQ 10
#define DEPTH 6

typedef float f32x2 __attribute__((ext_vector_type(2)));

__device__ __forceinline__ f32x2 bc(float x){ return (f32x2){x, x}; }
__device__ __forceinline__ f32x2 fma2(f32x2 a, f32x2 b, f32x2 c){
  return __builtin_elementwise_fma(a, b, c);
}

// ---- constexpr GF(2) tracking of the CNOT ring (sequential, matches ref) ----
struct Tables {
  int m[DEPTH][NQ];
  int R[DEPTH][NQ];
  int meas[NQ];
};
constexpr Tables make_tables(){
  Tables t{};
  int cols[NQ] = {}, rows[NQ] = {};
  for (int i = 0; i < NQ; ++i){ cols[i] = 1 << i; rows[i] = 1 << i; }
  for (int d = 0; d < DEPTH; ++d){
    for (int q = 0; q < NQ; ++q){ t.m[d][q] = cols[q]; t.R[d][q] = rows[q]; }
    for (int c = 0; c < NQ; ++c){
      int tt = (c + 1) % NQ;
      cols[c]  ^= cols[tt];
      rows[tt] ^= rows[c];
    }
  }
  for (int q = 0; q < NQ; ++q) t.meas[q] = rows[q];
  return t;
}
constexpr Tables TAB = make_tables();

// ---- storage-basis (R15): 5 reg bits + 5 lane bits, lane bit5 = sample ----
// storage bits 0-4 = logical 0-4 (reg r); bits 5-8 = logical 5-8 (lane l0-l3);
// bit 9 = parity of ALL logical bits (lane l4). Logical 9 is parity-encoded:
// n9 = s9 ^ (s0^..^s8).
constexpr int SM5(int m){
  return (m & 0x1FF) | ((__builtin_popcount(m) & 1) << 9);
}
// functional: F·n = sum_{i<=8}(F_i^F_9) s_i  ^  F_9 s_9
constexpr int FT5(int F){
  int f9 = (F >> 9) & 1;
  return ((F & 0x1FF) ^ (f9 ? 0x1FF : 0)) | (f9 << 9);
}

// ---- monotone float<->uint key for atomicMax over signed floats ----
__device__ __forceinline__ unsigned fkey(float x){
  unsigned b = __float_as_uint(x);
  return (b & 0x80000000u) ? ~b : (b | 0x80000000u);
}
__device__ __forceinline__ float funkey(unsigned k){
  unsigned b = (k & 0x80000000u) ? (k ^ 0x80000000u) : ~k;
  return __uint_as_float(b);
}

// ======== lane-xor machinery: DPP masks 1..15, ds_swizzle 16..31 ========
constexpr int quadctl(int m){ return (0^m) | ((1^m)<<2) | ((2^m)<<4) | ((3^m)<<6); }

template<int CTRL>
__device__ __forceinline__ float dppf(float x){
  return __uint_as_float((unsigned)__builtin_amdgcn_update_dpp(
      0, (int)__float_as_uint(x), CTRL, 0xF, 0xF, true));
}
template<int LM>     // 1..31: xor within 32-lane halves, single DS op
__device__ __forceinline__ float dsswz(float x){
  return __uint_as_float((unsigned)__builtin_amdgcn_ds_swizzle(
      (int)__float_as_uint(x), (LM << 10) | 0x1F));
}
template<int LM>   // 1..15 (within 16-lane rows, VALU pipe)
__device__ __forceinline__ float lxs(float x){
  if constexpr (LM == 0){
    return x;
  } else if constexpr (LM <= 3){
    return dppf<quadctl(LM)>(x);
  } else if constexpr (LM == 7){
    return dppf<0x141>(x);
  } else if constexpr (LM == 8){
    return dppf<0x128>(x);
  } else if constexpr (LM == 15){
    return dppf<0x140>(x);
  } else if constexpr ((LM & 12) == 4){
    return lxs<LM ^ 7>(dppf<0x141>(x));
  } else if constexpr ((LM & 12) == 8){
    return lxs<LM ^ 8>(dppf<0x128>(x));
  } else {
    return lxs<LM ^ 15>(dppf<0x140>(x));
  }
}
template<int LM>   // generic 5-bit lane exchange (within 32-lane halves)
__device__ __forceinline__ f32x2 lex(f32x2 v){
  f32x2 r;
  if constexpr (LM <= 15){
    r.x = lxs<LM>(v.x);
    r.y = lxs<LM>(v.y);
  } else {
    r.x = dsswz<LM>(v.x);
    r.y = dsswz<LM>(v.y);
  }
  return r;
}

// ---- prep ----
__global__ __launch_bounds__(256) void k_prep(const float* __restrict__ wts,
    const float* __restrict__ fcW,
    float4* __restrict__ U0,     // 20
    float* __restrict__ gcT,     // 50: tan(ax)
    float2* __restrict__ phase,  // 4*1024: (c,s) per storage index, layers 1..4
    float* __restrict__ fcWs,    // 40: fcW * (prod cos)^2
    unsigned* __restrict__ gkey)
{
  int idx = blockIdx.x * 256 + threadIdx.x;
  if (idx < 4096){
    int layer = 1 + (idx >> 10);
    int p = idx & 1023;          // STORAGE index (bits0-4 reg, 5-9 lane)
    float phi = 0.f;
    for (int q = 0; q < NQ; ++q){
      float az = wts[(layer*NQ + q)*2 + 1] * 0.5f;
      int Fs = FT5(TAB.R[layer][q]);
      phi += (__popc(Fs & p) & 1) ? az : -az;
    }
    phase[idx] = make_float2(cosf(phi), sinf(phi));
  }
  if (blockIdx.x == 0){
    int t = threadIdx.x;
    if (t < NQ){
      float ax = wts[t*2+0]*0.5f, az = wts[t*2+1]*0.5f;
      float ca=cosf(ax), sa=sinf(ax), cz=cosf(az), sz=sinf(az);
      U0[t*2+0] = make_float4(ca*cz, -ca*sz, -sa*sz, -sa*cz);
      U0[t*2+1] = make_float4(sa*sz, -sa*cz,  ca*cz,  ca*sz);
    } else if (t >= 64 && t < 64 + 50){
      int g = t - 64;
      int d = 1 + g/10, q = g % 10;
      float ax = wts[(d*NQ+q)*2+0]*0.5f;
      gcT[g] = tanf(ax);
    } else if (t == 120){
      *gkey = 0u;
    } else if (t == 121){
      float pc = 1.f;
      for (int g = 0; g < 50; ++g){
        int d = 1 + g/10, q = g % 10;
        pc *= cosf(wts[(d*NQ+q)*2+0]*0.5f);
      }
      float s2 = pc * pc;
      for (int j = 0; j < 40; ++j) fcWs[j] = fcW[j] * s2;
    }
  }
}

// ---- K1: coalesced LDS-staged pool -> encode -> global max (R10, proven) ----
__global__ __launch_bounds__(256) void k1_encode(const float* __restrict__ x,
    const float* __restrict__ encW, const float* __restrict__ encB,
    float* __restrict__ encOut, unsigned* __restrict__ gkey)
{
  __shared__ float lds[4][788];
  __shared__ float poolS[4][16];
  __shared__ float wmax[4];
  int tid = threadIdx.x, lane = tid & 63, wid = tid >> 6;
  float bm = -INFINITY;

  #pragma unroll 1
  for (int it = 0; it < 4; ++it){
    int s = blockIdx.x * 16 + it * 4 + wid;
    const float4* xs4 = reinterpret_cast<const float4*>(x + (size_t)s * 784);
    float4* l4 = reinterpret_cast<float4*>(lds[wid]);
    l4[lane]       = xs4[lane];
    l4[lane + 64]  = xs4[lane + 64];
    l4[lane + 128] = xs4[lane + 128];
    if (lane < 4) l4[lane + 192] = xs4[lane + 192];
    __syncthreads();
    int b = lane & 15, sub = lane >> 4;
    int r0 = (b >> 2) * 6, c0 = (b & 3) * 6;
    float acc = 0.f;
    #pragma unroll
    for (int k = 0; k < 9; ++k){
      int e = sub * 9 + k;
      acc += lds[wid][(r0 + e / 6) * 28 + c0 + e % 6];
    }
    acc += __shfl_xor(acc, 16, 64);
    acc += __shfl_xor(acc, 32, 64);
    if (lane < 16) poolS[wid][lane] = acc * (1.f/36.f);
    __syncthreads();
    float ev = -INFINITY;
    if (lane < NQ){
      float e = encB[lane];
      #pragma unroll
      for (int k = 0; k < 16; ++k) e = fmaf(poolS[wid][k], encW[lane*16+k], e);
      encOut[(size_t)s*NQ + lane] = e;
      ev = e;
    }
    #pragma unroll
    for (int st = 1; st < 16; st <<= 1) ev = fmaxf(ev, __shfl_xor(ev, st, 64));
    bm = fmaxf(bm, ev);
  }
  if (lane == 0) wmax[wid] = bm;
  __syncthreads();
  if (tid == 0){
    float mm = fmaxf(fmaxf(wmax[0], wmax[1]), fmaxf(wmax[2], wmax[3]));
    atomicMax(gkey, fkey(mm));
  }
}

// ---- Rx gate, tangent form, 5-lane-bit storage basis ----
template<int D, int Q>
__device__ __forceinline__ void rx_gate(f32x2 (&re)[32], f32x2 (&im)[32],
    const float* __restrict__ gcT)
{
  constexpr int ms = SM5(TAB.m[D][Q]);
  constexpr int rm = ms & 31;
  constexpr int lm = ms >> 5;
  float Tt = gcT[(D-1)*NQ + Q];
  f32x2 T = bc(Tt), nT = bc(-Tt);

  if constexpr (lm == 0){
    constexpr int lb = rm & (-rm);
    #pragma unroll
    for (int r = 0; r < 32; ++r) if (!(r & lb)){
      int r2 = r ^ rm;
      f32x2 ar = re[r],  ai = im[r];
      f32x2 br = re[r2], bi = im[r2];
      re[r]  = fma2(T,  bi, ar);
      im[r]  = fma2(nT, br, ai);
      re[r2] = fma2(T,  ai, br);
      im[r2] = fma2(nT, ar, bi);
    }
  } else if constexpr (rm == 0){
    #pragma unroll
    for (int r = 0; r < 32; ++r){
      f32x2 bi = lex<lm>(im[r]);
      f32x2 br = lex<lm>(re[r]);
      re[r] = fma2(T,  bi, re[r]);
      im[r] = fma2(nT, br, im[r]);
    }
  } else {
    constexpr int lb = rm & (-rm);
    #pragma unroll
    for (int r = 0; r < 32; ++r) if (!(r & lb)){
      int r2 = r ^ rm;
      f32x2 bi2 = lex<lm>(im[r2]);
      f32x2 br2 = lex<lm>(re[r2]);
      f32x2 bi1 = lex<lm>(im[r]);
      f32x2 br1 = lex<lm>(re[r]);
      re[r]  = fma2(T,  bi2, re[r]);
      im[r]  = fma2(nT, br2, im[r]);
      re[r2] = fma2(T,  bi1, re[r2]);
      im[r2] = fma2(nT, br1, im[r2]);
    }
  }
}

template<int D>
__device__ __forceinline__ void run_layer(f32x2 (&re)[32], f32x2 (&im)[32],
    const float* __restrict__ gcT, const float2* __restrict__ phase2, int l5)
{
  rx_gate<D,0>(re, im, gcT);
  rx_gate<D,1>(re, im, gcT);
  rx_gate<D,2>(re, im, gcT);
  rx_gate<D,3>(re, im, gcT);
  rx_gate<D,4>(re, im, gcT);
  rx_gate<D,5>(re, im, gcT);
  rx_gate<D,6>(re, im, gcT);
  rx_gate<D,7>(re, im, gcT);
  rx_gate<D,8>(re, im, gcT);
  rx_gate<D,9>(re, im, gcT);
  if constexpr (D <= 4){
    const float2* __restrict__ pp = phase2 + (size_t)(D-1)*1024 + l5*32;
    #pragma unroll
    for (int r = 0; r < 32; ++r){
      float2 ph = pp[r];                  // same diagonal for both samples
      f32x2 cp = bc(ph.x), sp = bc(ph.y);
      f32x2 ar = re[r], ai = im[r];
      re[r] = fma2(-sp, ai, cp*ar);
      im[r] = fma2( sp, ar, cp*ai);
    }
  }
}

// ---- K2: one wave per FOUR samples (f32x2 pair x wave-half pair) ----
// storage: bits0-4 = reg, bits5-9 = lane bits 0-4; lane bit5 = sample pair
__global__ __launch_bounds__(256) void k2_qsim(
    const float* __restrict__ enc, const unsigned* __restrict__ gkey,
    const float4* __restrict__ U0, const float* __restrict__ gcT,
    const float2* __restrict__ phase2,
    const float* __restrict__ fcWs, const float* __restrict__ fcB,
    float* __restrict__ outB)
{
  int tid  = threadIdx.x;
  int lane = tid & 63;
  int wid  = tid >> 6;
  int l5   = lane & 31;
  int sA   = blockIdx.x * 16 + wid * 4 + ((lane >> 5) << 1);
  int sB   = sA + 1;

  float invr = 3.14159265358979f / (funkey(*gkey) + 1e-8f);

  // lane-qubit product: logical 5..8 on lane bits 0..3
  f32x2 lr, li;
  #pragma unroll
  for (int j = 0; j < 4; ++j){
    int q = 5 + j;
    float angA = enc[(size_t)sA*NQ + q] * invr;
    float angB = enc[(size_t)sB*NQ + q] * invr;
    f32x2 cv = {__cosf(angA), __cosf(angB)};
    f32x2 sv = {__sinf(angA), __sinf(angB)};
    float4 a = U0[q*2+0], b = U0[q*2+1];
    f32x2 pa_r = fma2(bc(a.z), sv, bc(a.x)*cv);
    f32x2 pa_i = fma2(bc(a.w), sv, bc(a.y)*cv);
    f32x2 pb_r = fma2(bc(b.z), sv, bc(b.x)*cv);
    f32x2 pb_i = fma2(bc(b.w), sv, bc(b.y)*cv);
    bool bit = (l5 >> j) & 1;
    f32x2 fr = bit ? pb_r : pa_r;
    f32x2 fi = bit ? pb_i : pa_i;
    if (j == 0){ lr = fr; li = fi; }
    else {
      f32x2 t = lr*fr - li*fi;
      li = fma2(lr, fi, li*fr);
      lr = t;
    }
  }

  // parity-encoded logical 9: n9 = l4 ^ parity(l0..l3) ^ parity(r)
  f32x2 A0r, A0i, A1r, A1i;
  {
    float angA = enc[(size_t)sA*NQ + 9] * invr;
    float angB = enc[(size_t)sB*NQ + 9] * invr;
    f32x2 cv = {__cosf(angA), __cosf(angB)};
    f32x2 sv = {__sinf(angA), __sinf(angB)};
    float4 a = U0[18], b = U0[19];
    f32x2 pa_r = fma2(bc(a.z), sv, bc(a.x)*cv);
    f32x2 pa_i = fma2(bc(a.w), sv, bc(a.y)*cv);
    f32x2 pb_r = fma2(bc(b.z), sv, bc(b.x)*cv);
    f32x2 pb_i = fma2(bc(b.w), sv, bc(b.y)*cv);
    bool e = ((l5 >> 4) ^ __popc(l5 & 15)) & 1;
    A0r = e ? pb_r : pa_r;  A0i = e ? pb_i : pa_i;   // popc(r) even
    A1r = e ? pa_r : pb_r;  A1i = e ? pa_i : pb_i;   // popc(r) odd
  }

  // register-qubit product tree: logical 0..4 on reg bits 0..4
  f32x2 re[32], im[32];
  re[0] = lr; im[0] = li;
  #pragma unroll
  for (int k = 0; k < 5; ++k){
    float angA = enc[(size_t)sA*NQ + k] * invr;
    float angB = enc[(size_t)sB*NQ + k] * invr;
    f32x2 cv = {__cosf(angA), __cosf(angB)};
    f32x2 sv = {__sinf(angA), __sinf(angB)};
    float4 a = U0[k*2+0], b = U0[k*2+1];
    f32x2 pa_r = fma2(bc(a.z), sv, bc(a.x)*cv);
    f32x2 pa_i = fma2(bc(a.w), sv, bc(a.y)*cv);
    f32x2 pb_r = fma2(bc(b.z), sv, bc(b.x)*cv);
    f32x2 pb_i = fma2(bc(b.w), sv, bc(b.y)*cv);
    int w = 1 << k;
    #pragma unroll
    for (int r = 0; r < 16; ++r) if (r < w){
      f32x2 xr = re[r], xi = im[r];
      re[r|w] = xr*pb_r - xi*pb_i;
      im[r|w] = fma2(xr, pb_i, xi*pb_r);
      re[r]   = xr*pa_r - xi*pa_i;
      im[r]   = fma2(xr, pa_i, xi*pa_r);
    }
  }
  // fold in the parity-encoded qubit-9 factor (compile-time select per r)
  #pragma unroll
  for (int r = 0; r < 32; ++r){
    f32x2 sr = (__builtin_popcount(r) & 1) ? A1r : A0r;
    f32x2 si = (__builtin_popcount(r) & 1) ? A1i : A0i;
    f32x2 xr = re[r], xi = im[r];
    re[r] = xr*sr - xi*si;
    im[r] = fma2(xr, si, xi*sr);
  }

  run_layer<1>(re, im, gcT, phase2, l5);
  run_layer<2>(re, im, gcT, phase2, l5);
  run_layer<3>(re, im, gcT, phase2, l5);
  run_layer<4>(re, im, gcT, phase2, l5);
  run_layer<5>(re, im, gcT, phase2, l5);

  // probabilities -> 32-point WHT over reg bits
  f32x2 p2[32];
  #pragma unroll
  for (int r = 0; r < 32; ++r) p2[r] = fma2(re[r], re[r], im[r]*im[r]);
  #pragma unroll
  for (int k = 0; k < 5; ++k){
    int w = 1 << k;
    #pragma unroll
    for (int r = 0; r < 32; ++r) if (!(r & w)){
      f32x2 a = p2[r], b = p2[r|w];
      p2[r] = a + b; p2[r|w] = a - b;
    }
  }
  // z_q partial = +/- p2[Rs&31], sign from lane bits 0..4; fuse FC
  f32x2 o2[4] = {{0.f,0.f},{0.f,0.f},{0.f,0.f},{0.f,0.f}};
  #pragma unroll
  for (int q = 0; q < NQ; ++q){
    constexpr int RALL[NQ] = {FT5(TAB.meas[0]),FT5(TAB.meas[1]),FT5(TAB.meas[2]),
                              FT5(TAB.meas[3]),FT5(TAB.meas[4]),FT5(TAB.meas[5]),
                              FT5(TAB.meas[6]),FT5(TAB.meas[7]),FT5(TAB.meas[8]),
                              FT5(TAB.meas[9])};
    int R = RALL[q];
    f32x2 tq = p2[R & 31];
    unsigned sg = (unsigned)(__popc((R >> 5) & l5) << 31);
    tq.x = __uint_as_float(__float_as_uint(tq.x) ^ sg);
    tq.y = __uint_as_float(__float_as_uint(tq.y) ^ sg);
    #pragma unroll
    for (int j = 0; j < 4; ++j) o2[j] = fma2(tq, bc(fcWs[j*NQ + q]), o2[j]);
  }
  // butterfly reduce over lane bits 0..4 (within each 32-lane half)
  #pragma unroll
  for (int j = 0; j < 4; ++j){
    o2[j].x += lxs<1>(o2[j].x);   o2[j].y += lxs<1>(o2[j].y);
    o2[j].x += lxs<2>(o2[j].x);   o2[j].y += lxs<2>(o2[j].y);
    o2[j].x += lxs<4>(o2[j].x);   o2[j].y += lxs<4>(o2[j].y);
    o2[j].x += lxs<8>(o2[j].x);   o2[j].y += lxs<8>(o2[j].y);
    o2[j].x += dsswz<16>(o2[j].x);
    o2[j].y += dsswz<16>(o2[j].y);
  }
  if (l5 == 0){    // lane 0 writes samples sA,sB of half 0; lane 32 of half 1
    float4 a4 = make_float4(o2[0].x+fcB[0], o2[1].x+fcB[1], o2[2].x+fcB[2], o2[3].x+fcB[3]);
    float4 b4 = make_float4(o2[0].y+fcB[0], o2[1].y+fcB[1], o2[2].y+fcB[2], o2[3].y+fcB[3]);
    *reinterpret_cast<float4*>(&outB[(size_t)sA*4]) = a4;
    *reinterpret_cast<float4*>(&outB[(size_t)sB*4]) = b4;
  }
}

// ---- K3: deterministic BN stats (single block) ----
__global__ __launch_bounds__(1024) void k3_stats(const float* __restrict__ outB,
                                                 float* __restrict__ stats)
{
  int tid = threadIdx.x;
  float sum[4] = {0,0,0,0}, sq[4] = {0,0,0,0};
  for (int row = tid; row < B_SZ; row += 1024){
    float4 v = *reinterpret_cast<const float4*>(outB + (size_t)row*4);
    sum[0]+=v.x; sq[0]+=v.x*v.x;
    sum[1]+=v.y; sq[1]+=v.y*v.y;
    sum[2]+=v.z; sq[2]+=v.z*v.z;
    sum[3]+=v.w; sq[3]+=v.w*v.w;
  }
  #pragma unroll
  for (int k = 0; k < 4; ++k){
    #pragma unroll
    for (int st = 1; st < 64; st <<= 1){
      sum[k] += __shfl_xor(sum[k], st, 64);
      sq[k]  += __shfl_xor(sq[k],  st, 64);
    }
  }
  __shared__ float ls[16][8];
  int lane = tid & 63, w = tid >> 6;
  if (lane == 0){
    #pragma unroll
    for (int k = 0; k < 4; ++k){ ls[w][k] = sum[k]; ls[w][4+k] = sq[k]; }
  }
  __syncthreads();
  if (tid == 0){
    float fs[8];
    #pragma unroll
    for (int k = 0; k < 8; ++k){
      float a = 0.f;
      for (int w2 = 0; w2 < 16; ++w2) a += ls[w2][k];
      fs[k] = a;
    }
    #pragma unroll
    for (int k = 0; k < 4; ++k){
      float mean = fs[k] * (1.f/B_SZ);
      float var  = fs[4+k] * (1.f/B_SZ) - mean*mean;
      stats[k]   = mean;
      stats[4+k] = rsqrtf(var + 1e-5f);
    }
  }
}

// ---- K4: apply BN (parallel, 256 blocks) ----
__global__ __launch_bounds__(256) void k4_bn(const float* __restrict__ outB,
    const float* __restrict__ stats, const float* __restrict__ gamma,
    const float* __restrict__ beta, float* __restrict__ out)
{
  int idx = blockIdx.x * 256 + threadIdx.x;
  int c = idx & 3;
  float v = outB[idx];
  out[idx] = gamma[c] * (v - stats[c]) * stats[4+c] + beta[c];
}

extern "C" void kernel_launch(void* const* d_in, const int* in_sizes, int n_in,
                              void* d_out, int out_size, void* d_ws, size_t ws_size,
                              hipStream_t stream)
{
  const float* x     = (const float*)d_in[0];
  const float* encW  = (const float*)d_in[1];
  const float* encB  = (const float*)d_in[2];
  const float* wts   = (const float*)d_in[3];
  const float* fcW   = (const float*)d_in[4];
  const float* fcB   = (const float*)d_in[5];
  const float* gamma = (const float*)d_in[6];
  const float* beta  = (const float*)d_in[7];

  char* ws = (char*)d_ws;
  unsigned* gkey  = (unsigned*)ws;                      // 4 B
  float4*  U0     = (float4*)(ws + 256);                // 320 B
  float*   gcT    = (float*)(ws + 1024);                // 200 B
  float*   fcWs   = (float*)(ws + 2048);                // 160 B
  float2*  phase  = (float2*)(ws + 4096);               // 32 KB (c,s)
  float*   enc    = (float*)(ws + 4096 + 65536);
  float*   outB   = (float*)(ws + 4096 + 65536 + (size_t)B_SZ*NQ*4);
  float*   stats  = (float*)(ws + 4096 + 65536 + (size_t)B_SZ*NQ*4 + (size_t)B_SZ*4*4);

  hipLaunchKernelGGL(k_prep, dim3(16), dim3(256), 0, stream, wts, fcW, U0, gcT, phase, fcWs, gkey);
  hipLaunchKernelGGL(k1_encode, dim3(B_SZ/16), dim3(256), 0, stream,
                     x, encW, encB, enc, gkey);
  hipLaunchKernelGGL(k2_qsim, dim3(B_SZ/16), dim3(256), 0, stream,
                     enc, gkey, U0, gcT, phase, fcWs, fcB, outB);
  hipLaunchKernelGGL(k3_stats, dim3(1), dim3(1024), 0, stream, outB, stats);
  hipLaunchKernelGGL(k4_bn, dim3(B_SZ*4/256), dim3(256), 0, stream,
                     outB, stats, gamma, beta, (float*)d_out);
}

// Round 17
// 137.552 us; speedup vs baseline: 1.2984x; 1.0407x over previous
//
#include <hip/hip_runtime.h>
#include <math.h>

#define B_SZ 16384
#define NQ 10
#define DEPTH 6

typedef float f32x2 __attribute__((ext_vector_type(2)));

__device__ __forceinline__ f32x2 bc(float x){ return (f32x2){x, x}; }
__device__ __forceinline__ f32x2 fma2(f32x2 a, f32x2 b, f32x2 c){
  return __builtin_elementwise_fma(a, b, c);
}

// ---- constexpr GF(2) tracking of the CNOT ring (sequential, matches ref) ----
struct Tables {
  int m[DEPTH][NQ];
  int R[DEPTH][NQ];
  int meas[NQ];
};
constexpr Tables make_tables(){
  Tables t{};
  int cols[NQ] = {}, rows[NQ] = {};
  for (int i = 0; i < NQ; ++i){ cols[i] = 1 << i; rows[i] = 1 << i; }
  for (int d = 0; d < DEPTH; ++d){
    for (int q = 0; q < NQ; ++q){ t.m[d][q] = cols[q]; t.R[d][q] = rows[q]; }
    for (int c = 0; c < NQ; ++c){
      int tt = (c + 1) % NQ;
      cols[c]  ^= cols[tt];
      rows[tt] ^= rows[c];
    }
  }
  for (int q = 0; q < NQ; ++q) t.meas[q] = rows[q];
  return t;
}
constexpr Tables TAB = make_tables();

// ---- storage-basis (R15, proven): 5 reg bits + 5 lane bits ----
// storage bits 0-4 = logical 0-4 (reg); 5-8 = logical 5-8 (lane l0-l3);
// bit 9 = parity of ALL logical bits (lane l4). Logical 9 parity-encoded.
constexpr int SM5(int m){
  return (m & 0x1FF) | ((__builtin_popcount(m) & 1) << 9);
}
constexpr int FT5(int F){
  int f9 = (F >> 9) & 1;
  return ((F & 0x1FF) ^ (f9 ? 0x1FF : 0)) | (f9 << 9);
}

// ---- monotone float<->uint key for atomicMax over signed floats ----
__device__ __forceinline__ unsigned fkey(float x){
  unsigned b = __float_as_uint(x);
  return (b & 0x80000000u) ? ~b : (b | 0x80000000u);
}
__device__ __forceinline__ float funkey(unsigned k){
  unsigned b = (k & 0x80000000u) ? (k ^ 0x80000000u) : ~k;
  return __uint_as_float(b);
}

// ======== lane-xor machinery: DPP masks 1..15, ds_swizzle 16..31 ========
constexpr int quadctl(int m){ return (0^m) | ((1^m)<<2) | ((2^m)<<4) | ((3^m)<<6); }

template<int CTRL>
__device__ __forceinline__ float dppf(float x){
  return __uint_as_float((unsigned)__builtin_amdgcn_update_dpp(
      0, (int)__float_as_uint(x), CTRL, 0xF, 0xF, true));
}
template<int LM>     // 1..31: xor within 32-lane halves, single DS op
__device__ __forceinline__ float dsswz(float x){
  return __uint_as_float((unsigned)__builtin_amdgcn_ds_swizzle(
      (int)__float_as_uint(x), (LM << 10) | 0x1F));
}
template<int LM>   // 1..15 (within 16-lane rows, VALU pipe)
__device__ __forceinline__ float lxs(float x){
  if constexpr (LM == 0){
    return x;
  } else if constexpr (LM <= 3){
    return dppf<quadctl(LM)>(x);
  } else if constexpr (LM == 7){
    return dppf<0x141>(x);
  } else if constexpr (LM == 8){
    return dppf<0x128>(x);
  } else if constexpr (LM == 15){
    return dppf<0x140>(x);
  } else if constexpr ((LM & 12) == 4){
    return lxs<LM ^ 7>(dppf<0x141>(x));
  } else if constexpr ((LM & 12) == 8){
    return lxs<LM ^ 8>(dppf<0x128>(x));
  } else {
    return lxs<LM ^ 15>(dppf<0x140>(x));
  }
}
template<int LM>   // generic 5-bit lane exchange (within 32-lane halves)
__device__ __forceinline__ f32x2 lex(f32x2 v){
  f32x2 r;
  if constexpr (LM <= 15){
    r.x = lxs<LM>(v.x);
    r.y = lxs<LM>(v.y);
  } else {
    r.x = dsswz<LM>(v.x);
    r.y = dsswz<LM>(v.y);
  }
  return r;
}

// ---- K1: fused prep + coalesced LDS-staged pool/encode + global max ----
// 1024 blocks: blocks 0-15 also fill the phase table, block 16 fills
// U0/gcT/fcWs. gkey is zeroed by hipMemsetAsync before launch.
__global__ __launch_bounds__(256) void k1_encode_prep(const float* __restrict__ x,
    const float* __restrict__ encW, const float* __restrict__ encB,
    const float* __restrict__ wts,  const float* __restrict__ fcW,
    float4* __restrict__ U0, float* __restrict__ gcT,
    float2* __restrict__ phase, float* __restrict__ fcWs,
    float* __restrict__ encOut, unsigned* __restrict__ gkey)
{
  int tid = threadIdx.x, lane = tid & 63, wid = tid >> 6;
  int bid = blockIdx.x;

  // ---- prep fragment (interleaved with encode work below) ----
  if (bid < 16){
    int idx = bid * 256 + tid;           // 4096 phase-table entries
    int layer = 1 + (idx >> 10);
    int p = idx & 1023;                  // STORAGE index
    float phi = 0.f;
    for (int q = 0; q < NQ; ++q){
      float az = wts[(layer*NQ + q)*2 + 1] * 0.5f;
      int Fs = FT5(TAB.R[layer][q]);
      phi += (__popc(Fs & p) & 1) ? az : -az;
    }
    phase[idx] = make_float2(cosf(phi), sinf(phi));
  } else if (bid == 16){
    if (tid < NQ){
      float ax = wts[tid*2+0]*0.5f, az = wts[tid*2+1]*0.5f;
      float ca=cosf(ax), sa=sinf(ax), cz=cosf(az), sz=sinf(az);
      U0[tid*2+0] = make_float4(ca*cz, -ca*sz, -sa*sz, -sa*cz);
      U0[tid*2+1] = make_float4(sa*sz, -sa*cz,  ca*cz,  ca*sz);
    } else if (tid >= 64 && tid < 64 + 50){
      int g = tid - 64;
      int d = 1 + g/10, q = g % 10;
      gcT[g] = tanf(wts[(d*NQ+q)*2+0]*0.5f);
    } else if (tid == 121){
      float pc = 1.f;
      for (int g = 0; g < 50; ++g){
        int d = 1 + g/10, q = g % 10;
        pc *= cosf(wts[(d*NQ+q)*2+0]*0.5f);
      }
      float s2 = pc * pc;
      for (int j = 0; j < 40; ++j) fcWs[j] = fcW[j] * s2;
    }
  }

  // ---- encode 16 samples (R10 structure, proven) ----
  __shared__ float lds[4][788];
  __shared__ float poolS[4][16];
  __shared__ float wmax[4];
  float bm = -INFINITY;

  #pragma unroll 1
  for (int it = 0; it < 4; ++it){
    int s = bid * 16 + it * 4 + wid;
    const float4* xs4 = reinterpret_cast<const float4*>(x + (size_t)s * 784);
    float4* l4 = reinterpret_cast<float4*>(lds[wid]);
    l4[lane]       = xs4[lane];
    l4[lane + 64]  = xs4[lane + 64];
    l4[lane + 128] = xs4[lane + 128];
    if (lane < 4) l4[lane + 192] = xs4[lane + 192];
    __syncthreads();
    int b = lane & 15, sub = lane >> 4;
    int r0 = (b >> 2) * 6, c0 = (b & 3) * 6;
    float acc = 0.f;
    #pragma unroll
    for (int k = 0; k < 9; ++k){
      int e = sub * 9 + k;
      acc += lds[wid][(r0 + e / 6) * 28 + c0 + e % 6];
    }
    acc += __shfl_xor(acc, 16, 64);
    acc += __shfl_xor(acc, 32, 64);
    if (lane < 16) poolS[wid][lane] = acc * (1.f/36.f);
    __syncthreads();
    float ev = -INFINITY;
    if (lane < NQ){
      float e = encB[lane];
      #pragma unroll
      for (int k = 0; k < 16; ++k) e = fmaf(poolS[wid][k], encW[lane*16+k], e);
      encOut[(size_t)s*NQ + lane] = e;
      ev = e;
    }
    #pragma unroll
    for (int st = 1; st < 16; st <<= 1) ev = fmaxf(ev, __shfl_xor(ev, st, 64));
    bm = fmaxf(bm, ev);
  }
  if (lane == 0) wmax[wid] = bm;
  __syncthreads();
  if (tid == 0){
    float mm = fmaxf(fmaxf(wmax[0], wmax[1]), fmaxf(wmax[2], wmax[3]));
    atomicMax(gkey, fkey(mm));
  }
}

// ---- Rx gate, tangent form, 5-lane-bit storage basis (R15, proven) ----
template<int D, int Q>
__device__ __forceinline__ void rx_gate(f32x2 (&re)[32], f32x2 (&im)[32],
    const float* __restrict__ gcT)
{
  constexpr int ms = SM5(TAB.m[D][Q]);
  constexpr int rm = ms & 31;
  constexpr int lm = ms >> 5;
  float Tt = gcT[(D-1)*NQ + Q];
  f32x2 T = bc(Tt), nT = bc(-Tt);

  if constexpr (lm == 0){
    constexpr int lb = rm & (-rm);
    #pragma unroll
    for (int r = 0; r < 32; ++r) if (!(r & lb)){
      int r2 = r ^ rm;
      f32x2 ar = re[r],  ai = im[r];
      f32x2 br = re[r2], bi = im[r2];
      re[r]  = fma2(T,  bi, ar);
      im[r]  = fma2(nT, br, ai);
      re[r2] = fma2(T,  ai, br);
      im[r2] = fma2(nT, ar, bi);
    }
  } else if constexpr (rm == 0){
    #pragma unroll
    for (int r = 0; r < 32; ++r){
      f32x2 bi = lex<lm>(im[r]);
      f32x2 br = lex<lm>(re[r]);
      re[r] = fma2(T,  bi, re[r]);
      im[r] = fma2(nT, br, im[r]);
    }
  } else {
    constexpr int lb = rm & (-rm);
    #pragma unroll
    for (int r = 0; r < 32; ++r) if (!(r & lb)){
      int r2 = r ^ rm;
      f32x2 bi2 = lex<lm>(im[r2]);
      f32x2 br2 = lex<lm>(re[r2]);
      f32x2 bi1 = lex<lm>(im[r]);
      f32x2 br1 = lex<lm>(re[r]);
      re[r]  = fma2(T,  bi2, re[r]);
      im[r]  = fma2(nT, br2, im[r]);
      re[r2] = fma2(T,  bi1, re[r2]);
      im[r2] = fma2(nT, br1, im[r2]);
    }
  }
}

template<int D>
__device__ __forceinline__ void run_layer(f32x2 (&re)[32], f32x2 (&im)[32],
    const float* __restrict__ gcT, const float2* __restrict__ phase2, int l5)
{
  rx_gate<D,0>(re, im, gcT);
  rx_gate<D,1>(re, im, gcT);
  rx_gate<D,2>(re, im, gcT);
  rx_gate<D,3>(re, im, gcT);
  rx_gate<D,4>(re, im, gcT);
  rx_gate<D,5>(re, im, gcT);
  rx_gate<D,6>(re, im, gcT);
  rx_gate<D,7>(re, im, gcT);
  rx_gate<D,8>(re, im, gcT);
  rx_gate<D,9>(re, im, gcT);
  if constexpr (D <= 4){
    const float2* __restrict__ pp = phase2 + (size_t)(D-1)*1024 + l5*32;
    #pragma unroll
    for (int r = 0; r < 32; ++r){
      float2 ph = pp[r];                  // same diagonal for both samples
      f32x2 cp = bc(ph.x), sp = bc(ph.y);
      f32x2 ar = re[r], ai = im[r];
      re[r] = fma2(-sp, ai, cp*ar);
      im[r] = fma2( sp, ar, cp*ai);
    }
  }
}

// ---- K2: one wave per FOUR samples (f32x2 pair x wave-half pair; R15) ----
__global__ __launch_bounds__(256) void k2_qsim(
    const float* __restrict__ enc, const unsigned* __restrict__ gkey,
    const float4* __restrict__ U0, const float* __restrict__ gcT,
    const float2* __restrict__ phase2,
    const float* __restrict__ fcWs, const float* __restrict__ fcB,
    float* __restrict__ outB)
{
  int tid  = threadIdx.x;
  int lane = tid & 63;
  int wid  = tid >> 6;
  int l5   = lane & 31;
  int sA   = blockIdx.x * 16 + wid * 4 + ((lane >> 5) << 1);
  int sB   = sA + 1;

  float invr = 3.14159265358979f / (funkey(*gkey) + 1e-8f);

  // lane-qubit product: logical 5..8 on lane bits 0..3
  f32x2 lr, li;
  #pragma unroll
  for (int j = 0; j < 4; ++j){
    int q = 5 + j;
    float angA = enc[(size_t)sA*NQ + q] * invr;
    float angB = enc[(size_t)sB*NQ + q] * invr;
    f32x2 cv = {__cosf(angA), __cosf(angB)};
    f32x2 sv = {__sinf(angA), __sinf(angB)};
    float4 a = U0[q*2+0], b = U0[q*2+1];
    f32x2 pa_r = fma2(bc(a.z), sv, bc(a.x)*cv);
    f32x2 pa_i = fma2(bc(a.w), sv, bc(a.y)*cv);
    f32x2 pb_r = fma2(bc(b.z), sv, bc(b.x)*cv);
    f32x2 pb_i = fma2(bc(b.w), sv, bc(b.y)*cv);
    bool bit = (l5 >> j) & 1;
    f32x2 fr = bit ? pb_r : pa_r;
    f32x2 fi = bit ? pb_i : pa_i;
    if (j == 0){ lr = fr; li = fi; }
    else {
      f32x2 t = lr*fr - li*fi;
      li = fma2(lr, fi, li*fr);
      lr = t;
    }
  }

  // parity-encoded logical 9: n9 = l4 ^ parity(l0..l3) ^ parity(r)
  f32x2 A0r, A0i, A1r, A1i;
  {
    float angA = enc[(size_t)sA*NQ + 9] * invr;
    float angB = enc[(size_t)sB*NQ + 9] * invr;
    f32x2 cv = {__cosf(angA), __cosf(angB)};
    f32x2 sv = {__sinf(angA), __sinf(angB)};
    float4 a = U0[18], b = U0[19];
    f32x2 pa_r = fma2(bc(a.z), sv, bc(a.x)*cv);
    f32x2 pa_i = fma2(bc(a.w), sv, bc(a.y)*cv);
    f32x2 pb_r = fma2(bc(b.z), sv, bc(b.x)*cv);
    f32x2 pb_i = fma2(bc(b.w), sv, bc(b.y)*cv);
    bool e = ((l5 >> 4) ^ __popc(l5 & 15)) & 1;
    A0r = e ? pb_r : pa_r;  A0i = e ? pb_i : pa_i;   // popc(r) even
    A1r = e ? pa_r : pb_r;  A1i = e ? pa_i : pb_i;   // popc(r) odd
  }

  // register-qubit product tree: logical 0..4 on reg bits 0..4
  f32x2 re[32], im[32];
  re[0] = lr; im[0] = li;
  #pragma unroll
  for (int k = 0; k < 5; ++k){
    float angA = enc[(size_t)sA*NQ + k] * invr;
    float angB = enc[(size_t)sB*NQ + k] * invr;
    f32x2 cv = {__cosf(angA), __cosf(angB)};
    f32x2 sv = {__sinf(angA), __sinf(angB)};
    float4 a = U0[k*2+0], b = U0[k*2+1];
    f32x2 pa_r = fma2(bc(a.z), sv, bc(a.x)*cv);
    f32x2 pa_i = fma2(bc(a.w), sv, bc(a.y)*cv);
    f32x2 pb_r = fma2(bc(b.z), sv, bc(b.x)*cv);
    f32x2 pb_i = fma2(bc(b.w), sv, bc(b.y)*cv);
    int w = 1 << k;
    #pragma unroll
    for (int r = 0; r < 16; ++r) if (r < w){
      f32x2 xr = re[r], xi = im[r];
      re[r|w] = xr*pb_r - xi*pb_i;
      im[r|w] = fma2(xr, pb_i, xi*pb_r);
      re[r]   = xr*pa_r - xi*pa_i;
      im[r]   = fma2(xr, pa_i, xi*pa_r);
    }
  }
  // fold in the parity-encoded qubit-9 factor (compile-time select per r)
  #pragma unroll
  for (int r = 0; r < 32; ++r){
    f32x2 sr = (__builtin_popcount(r) & 1) ? A1r : A0r;
    f32x2 si = (__builtin_popcount(r) & 1) ? A1i : A0i;
    f32x2 xr = re[r], xi = im[r];
    re[r] = xr*sr - xi*si;
    im[r] = fma2(xr, si, xi*sr);
  }

  run_layer<1>(re, im, gcT, phase2, l5);
  run_layer<2>(re, im, gcT, phase2, l5);
  run_layer<3>(re, im, gcT, phase2, l5);
  run_layer<4>(re, im, gcT, phase2, l5);
  run_layer<5>(re, im, gcT, phase2, l5);

  // probabilities -> 32-point WHT over reg bits
  f32x2 p2[32];
  #pragma unroll
  for (int r = 0; r < 32; ++r) p2[r] = fma2(re[r], re[r], im[r]*im[r]);
  #pragma unroll
  for (int k = 0; k < 5; ++k){
    int w = 1 << k;
    #pragma unroll
    for (int r = 0; r < 32; ++r) if (!(r & w)){
      f32x2 a = p2[r], b = p2[r|w];
      p2[r] = a + b; p2[r|w] = a - b;
    }
  }
  // z_q partial = +/- p2[Rs&31], sign from lane bits 0..4; fuse FC
  f32x2 o2[4] = {{0.f,0.f},{0.f,0.f},{0.f,0.f},{0.f,0.f}};
  #pragma unroll
  for (int q = 0; q < NQ; ++q){
    constexpr int RALL[NQ] = {FT5(TAB.meas[0]),FT5(TAB.meas[1]),FT5(TAB.meas[2]),
                              FT5(TAB.meas[3]),FT5(TAB.meas[4]),FT5(TAB.meas[5]),
                              FT5(TAB.meas[6]),FT5(TAB.meas[7]),FT5(TAB.meas[8]),
                              FT5(TAB.meas[9])};
    int R = RALL[q];
    f32x2 tq = p2[R & 31];
    unsigned sg = (unsigned)(__popc((R >> 5) & l5) << 31);
    tq.x = __uint_as_float(__float_as_uint(tq.x) ^ sg);
    tq.y = __uint_as_float(__float_as_uint(tq.y) ^ sg);
    #pragma unroll
    for (int j = 0; j < 4; ++j) o2[j] = fma2(tq, bc(fcWs[j*NQ + q]), o2[j]);
  }
  // butterfly reduce over lane bits 0..4 (within each 32-lane half)
  #pragma unroll
  for (int j = 0; j < 4; ++j){
    o2[j].x += lxs<1>(o2[j].x);   o2[j].y += lxs<1>(o2[j].y);
    o2[j].x += lxs<2>(o2[j].x);   o2[j].y += lxs<2>(o2[j].y);
    o2[j].x += lxs<4>(o2[j].x);   o2[j].y += lxs<4>(o2[j].y);
    o2[j].x += lxs<8>(o2[j].x);   o2[j].y += lxs<8>(o2[j].y);
    o2[j].x += dsswz<16>(o2[j].x);
    o2[j].y += dsswz<16>(o2[j].y);
  }
  if (l5 == 0){
    float4 a4 = make_float4(o2[0].x+fcB[0], o2[1].x+fcB[1], o2[2].x+fcB[2], o2[3].x+fcB[3]);
    float4 b4 = make_float4(o2[0].y+fcB[0], o2[1].y+fcB[1], o2[2].y+fcB[2], o2[3].y+fcB[3]);
    *reinterpret_cast<float4*>(&outB[(size_t)sA*4]) = a4;
    *reinterpret_cast<float4*>(&outB[(size_t)sB*4]) = b4;
  }
}

// ---- K3: deterministic BN stats (single block) ----
__global__ __launch_bounds__(1024) void k3_stats(const float* __restrict__ outB,
                                                 float* __restrict__ stats)
{
  int tid = threadIdx.x;
  float sum[4] = {0,0,0,0}, sq[4] = {0,0,0,0};
  for (int row = tid; row < B_SZ; row += 1024){
    float4 v = *reinterpret_cast<const float4*>(outB + (size_t)row*4);
    sum[0]+=v.x; sq[0]+=v.x*v.x;
    sum[1]+=v.y; sq[1]+=v.y*v.y;
    sum[2]+=v.z; sq[2]+=v.z*v.z;
    sum[3]+=v.w; sq[3]+=v.w*v.w;
  }
  #pragma unroll
  for (int k = 0; k < 4; ++k){
    #pragma unroll
    for (int st = 1; st < 64; st <<= 1){
      sum[k] += __shfl_xor(sum[k], st, 64);
      sq[k]  += __shfl_xor(sq[k],  st, 64);
    }
  }
  __shared__ float ls[16][8];
  int lane = tid & 63, w = tid >> 6;
  if (lane == 0){
    #pragma unroll
    for (int k = 0; k < 4; ++k){ ls[w][k] = sum[k]; ls[w][4+k] = sq[k]; }
  }
  __syncthreads();
  if (tid == 0){
    float fs[8];
    #pragma unroll
    for (int k = 0; k < 8; ++k){
      float a = 0.f;
      for (int w2 = 0; w2 < 16; ++w2) a += ls[w2][k];
      fs[k] = a;
    }
    #pragma unroll
    for (int k = 0; k < 4; ++k){
      float mean = fs[k] * (1.f/B_SZ);
      float var  = fs[4+k] * (1.f/B_SZ) - mean*mean;
      stats[k]   = mean;
      stats[4+k] = rsqrtf(var + 1e-5f);
    }
  }
}

// ---- K4: apply BN (parallel, 256 blocks) ----
__global__ __launch_bounds__(256) void k4_bn(const float* __restrict__ outB,
    const float* __restrict__ stats, const float* __restrict__ gamma,
    const float* __restrict__ beta, float* __restrict__ out)
{
  int idx = blockIdx.x * 256 + threadIdx.x;
  int c = idx & 3;
  float v = outB[idx];
  out[idx] = gamma[c] * (v - stats[c]) * stats[4+c] + beta[c];
}

extern "C" void kernel_launch(void* const* d_in, const int* in_sizes, int n_in,
                              void* d_out, int out_size, void* d_ws, size_t ws_size,
                              hipStream_t stream)
{
  const float* x     = (const float*)d_in[0];
  const float* encW  = (const float*)d_in[1];
  const float* encB  = (const float*)d_in[2];
  const float* wts   = (const float*)d_in[3];
  const float* fcW   = (const float*)d_in[4];
  const float* fcB   = (const float*)d_in[5];
  const float* gamma = (const float*)d_in[6];
  const float* beta  = (const float*)d_in[7];

  char* ws = (char*)d_ws;
  unsigned* gkey  = (unsigned*)ws;                      // 4 B
  float4*  U0     = (float4*)(ws + 256);                // 320 B
  float*   gcT    = (float*)(ws + 1024);                // 200 B
  float*   fcWs   = (float*)(ws + 2048);                // 160 B
  float2*  phase  = (float2*)(ws + 4096);               // 32 KB (c,s)
  float*   enc    = (float*)(ws + 4096 + 65536);
  float*   outB   = (float*)(ws + 4096 + 65536 + (size_t)B_SZ*NQ*4);
  float*   stats  = (float*)(ws + 4096 + 65536 + (size_t)B_SZ*NQ*4 + (size_t)B_SZ*4*4);

  hipMemsetAsync(gkey, 0, 4, stream);
  hipLaunchKernelGGL(k1_encode_prep, dim3(B_SZ/16), dim3(256), 0, stream,
                     x, encW, encB, wts, fcW, U0, gcT, phase, fcWs, enc, gkey);
  hipLaunchKernelGGL(k2_qsim, dim3(B_SZ/16), dim3(256), 0, stream,
                     enc, gkey, U0, gcT, phase, fcWs, fcB, outB);
  hipLaunchKernelGGL(k3_stats, dim3(1), dim3(1024), 0, stream, outB, stats);
  hipLaunchKernelGGL(k4_bn, dim3(B_SZ*4/256), dim3(256), 0, stream,
                     outB, stats, gamma, beta, (float*)d_out);
}

// Round 18
// 128.313 us; speedup vs baseline: 1.3918x; 1.0720x over previous
//
#include <hip/hip_runtime.h>
#include <math.h>

#define B_SZ 16384
#define NQ 10
#define DEPTH 6

#define SCALE_S 67108864.0f    // 2^26 for sums
#define SCALE_Q 16777216.0f    // 2^24 for sum-of-squares

typedef float f32x2 __attribute__((ext_vector_type(2)));

__device__ __forceinline__ f32x2 bc(float x){ return (f32x2){x, x}; }
__device__ __forceinline__ f32x2 fma2(f32x2 a, f32x2 b, f32x2 c){
  return __builtin_elementwise_fma(a, b, c);
}

// ---- constexpr GF(2) tracking of the CNOT ring (sequential, matches ref) ----
struct Tables {
  int m[DEPTH][NQ];
  int R[DEPTH][NQ];
  int meas[NQ];
};
constexpr Tables make_tables(){
  Tables t{};
  int cols[NQ] = {}, rows[NQ] = {};
  for (int i = 0; i < NQ; ++i){ cols[i] = 1 << i; rows[i] = 1 << i; }
  for (int d = 0; d < DEPTH; ++d){
    for (int q = 0; q < NQ; ++q){ t.m[d][q] = cols[q]; t.R[d][q] = rows[q]; }
    for (int c = 0; c < NQ; ++c){
      int tt = (c + 1) % NQ;
      cols[c]  ^= cols[tt];
      rows[tt] ^= rows[c];
    }
  }
  for (int q = 0; q < NQ; ++q) t.meas[q] = rows[q];
  return t;
}
constexpr Tables TAB = make_tables();

// ---- storage-basis (R15, proven): 5 reg bits + 5 lane bits ----
constexpr int SM5(int m){
  return (m & 0x1FF) | ((__builtin_popcount(m) & 1) << 9);
}
constexpr int FT5(int F){
  int f9 = (F >> 9) & 1;
  return ((F & 0x1FF) ^ (f9 ? 0x1FF : 0)) | (f9 << 9);
}

// ---- monotone float<->uint key for atomicMax over signed floats ----
__device__ __forceinline__ unsigned fkey(float x){
  unsigned b = __float_as_uint(x);
  return (b & 0x80000000u) ? ~b : (b | 0x80000000u);
}
__device__ __forceinline__ float funkey(unsigned k){
  unsigned b = (k & 0x80000000u) ? (k ^ 0x80000000u) : ~k;
  return __uint_as_float(b);
}

// ======== lane-xor machinery: DPP masks 1..15, ds_swizzle 16..31 ========
constexpr int quadctl(int m){ return (0^m) | ((1^m)<<2) | ((2^m)<<4) | ((3^m)<<6); }

template<int CTRL>
__device__ __forceinline__ float dppf(float x){
  return __uint_as_float((unsigned)__builtin_amdgcn_update_dpp(
      0, (int)__float_as_uint(x), CTRL, 0xF, 0xF, true));
}
template<int LM>     // 1..31: xor within 32-lane halves, single DS op
__device__ __forceinline__ float dsswz(float x){
  return __uint_as_float((unsigned)__builtin_amdgcn_ds_swizzle(
      (int)__float_as_uint(x), (LM << 10) | 0x1F));
}
template<int LM>   // 1..15 (within 16-lane rows, VALU pipe)
__device__ __forceinline__ float lxs(float x){
  if constexpr (LM == 0){
    return x;
  } else if constexpr (LM <= 3){
    return dppf<quadctl(LM)>(x);
  } else if constexpr (LM == 7){
    return dppf<0x141>(x);
  } else if constexpr (LM == 8){
    return dppf<0x128>(x);
  } else if constexpr (LM == 15){
    return dppf<0x140>(x);
  } else if constexpr ((LM & 12) == 4){
    return lxs<LM ^ 7>(dppf<0x141>(x));
  } else if constexpr ((LM & 12) == 8){
    return lxs<LM ^ 8>(dppf<0x128>(x));
  } else {
    return lxs<LM ^ 15>(dppf<0x140>(x));
  }
}
template<int LM>   // generic 5-bit lane exchange (within 32-lane halves)
__device__ __forceinline__ f32x2 lex(f32x2 v){
  f32x2 r;
  if constexpr (LM <= 15){
    r.x = lxs<LM>(v.x);
    r.y = lxs<LM>(v.y);
  } else {
    r.x = dsswz<LM>(v.x);
    r.y = dsswz<LM>(v.y);
  }
  return r;
}

// ---- K1: fused prep + coalesced LDS-staged pool/encode + global max ----
__global__ __launch_bounds__(256) void k1_encode_prep(const float* __restrict__ x,
    const float* __restrict__ encW, const float* __restrict__ encB,
    const float* __restrict__ wts,  const float* __restrict__ fcW,
    float4* __restrict__ U0, float* __restrict__ gcT,
    float2* __restrict__ phase, float* __restrict__ fcWs,
    float* __restrict__ encOut, unsigned* __restrict__ gkey)
{
  int tid = threadIdx.x, lane = tid & 63, wid = tid >> 6;
  int bid = blockIdx.x;

  if (bid < 16){
    int idx = bid * 256 + tid;           // 4096 phase-table entries
    int layer = 1 + (idx >> 10);
    int p = idx & 1023;                  // STORAGE index
    float phi = 0.f;
    for (int q = 0; q < NQ; ++q){
      float az = wts[(layer*NQ + q)*2 + 1] * 0.5f;
      int Fs = FT5(TAB.R[layer][q]);
      phi += (__popc(Fs & p) & 1) ? az : -az;
    }
    phase[idx] = make_float2(cosf(phi), sinf(phi));
  } else if (bid == 16){
    if (tid < NQ){
      float ax = wts[tid*2+0]*0.5f, az = wts[tid*2+1]*0.5f;
      float ca=cosf(ax), sa=sinf(ax), cz=cosf(az), sz=sinf(az);
      U0[tid*2+0] = make_float4(ca*cz, -ca*sz, -sa*sz, -sa*cz);
      U0[tid*2+1] = make_float4(sa*sz, -sa*cz,  ca*cz,  ca*sz);
    } else if (tid >= 64 && tid < 64 + 50){
      int g = tid - 64;
      int d = 1 + g/10, q = g % 10;
      gcT[g] = tanf(wts[(d*NQ+q)*2+0]*0.5f);
    } else if (tid == 121){
      float pc = 1.f;
      for (int g = 0; g < 50; ++g){
        int d = 1 + g/10, q = g % 10;
        pc *= cosf(wts[(d*NQ+q)*2+0]*0.5f);
      }
      float s2 = pc * pc;
      for (int j = 0; j < 40; ++j) fcWs[j] = fcW[j] * s2;
    }
  }

  __shared__ float lds[4][788];
  __shared__ float poolS[4][16];
  __shared__ float wmax[4];
  float bm = -INFINITY;

  #pragma unroll 1
  for (int it = 0; it < 4; ++it){
    int s = bid * 16 + it * 4 + wid;
    const float4* xs4 = reinterpret_cast<const float4*>(x + (size_t)s * 784);
    float4* l4 = reinterpret_cast<float4*>(lds[wid]);
    l4[lane]       = xs4[lane];
    l4[lane + 64]  = xs4[lane + 64];
    l4[lane + 128] = xs4[lane + 128];
    if (lane < 4) l4[lane + 192] = xs4[lane + 192];
    __syncthreads();
    int b = lane & 15, sub = lane >> 4;
    int r0 = (b >> 2) * 6, c0 = (b & 3) * 6;
    float acc = 0.f;
    #pragma unroll
    for (int k = 0; k < 9; ++k){
      int e = sub * 9 + k;
      acc += lds[wid][(r0 + e / 6) * 28 + c0 + e % 6];
    }
    acc += __shfl_xor(acc, 16, 64);
    acc += __shfl_xor(acc, 32, 64);
    if (lane < 16) poolS[wid][lane] = acc * (1.f/36.f);
    __syncthreads();
    float ev = -INFINITY;
    if (lane < NQ){
      float e = encB[lane];
      #pragma unroll
      for (int k = 0; k < 16; ++k) e = fmaf(poolS[wid][k], encW[lane*16+k], e);
      encOut[(size_t)s*NQ + lane] = e;
      ev = e;
    }
    #pragma unroll
    for (int st = 1; st < 16; st <<= 1) ev = fmaxf(ev, __shfl_xor(ev, st, 64));
    bm = fmaxf(bm, ev);
  }
  if (lane == 0) wmax[wid] = bm;
  __syncthreads();
  if (tid == 0){
    float mm = fmaxf(fmaxf(wmax[0], wmax[1]), fmaxf(wmax[2], wmax[3]));
    atomicMax(gkey, fkey(mm));
  }
}

// ---- Rx gate, tangent form, 5-lane-bit storage basis (R15, proven) ----
template<int D, int Q>
__device__ __forceinline__ void rx_gate(f32x2 (&re)[32], f32x2 (&im)[32],
    const float* __restrict__ gcT)
{
  constexpr int ms = SM5(TAB.m[D][Q]);
  constexpr int rm = ms & 31;
  constexpr int lm = ms >> 5;
  float Tt = gcT[(D-1)*NQ + Q];
  f32x2 T = bc(Tt), nT = bc(-Tt);

  if constexpr (lm == 0){
    constexpr int lb = rm & (-rm);
    #pragma unroll
    for (int r = 0; r < 32; ++r) if (!(r & lb)){
      int r2 = r ^ rm;
      f32x2 ar = re[r],  ai = im[r];
      f32x2 br = re[r2], bi = im[r2];
      re[r]  = fma2(T,  bi, ar);
      im[r]  = fma2(nT, br, ai);
      re[r2] = fma2(T,  ai, br);
      im[r2] = fma2(nT, ar, bi);
    }
  } else if constexpr (rm == 0){
    #pragma unroll
    for (int r = 0; r < 32; ++r){
      f32x2 bi = lex<lm>(im[r]);
      f32x2 br = lex<lm>(re[r]);
      re[r] = fma2(T,  bi, re[r]);
      im[r] = fma2(nT, br, im[r]);
    }
  } else {
    constexpr int lb = rm & (-rm);
    #pragma unroll
    for (int r = 0; r < 32; ++r) if (!(r & lb)){
      int r2 = r ^ rm;
      f32x2 bi2 = lex<lm>(im[r2]);
      f32x2 br2 = lex<lm>(re[r2]);
      f32x2 bi1 = lex<lm>(im[r]);
      f32x2 br1 = lex<lm>(re[r]);
      re[r]  = fma2(T,  bi2, re[r]);
      im[r]  = fma2(nT, br2, im[r]);
      re[r2] = fma2(T,  bi1, re[r2]);
      im[r2] = fma2(nT, br1, im[r2]);
    }
  }
}

template<int D>
__device__ __forceinline__ void run_layer(f32x2 (&re)[32], f32x2 (&im)[32],
    const float* __restrict__ gcT, const float2* __restrict__ phase2, int l5)
{
  rx_gate<D,0>(re, im, gcT);
  rx_gate<D,1>(re, im, gcT);
  rx_gate<D,2>(re, im, gcT);
  rx_gate<D,3>(re, im, gcT);
  rx_gate<D,4>(re, im, gcT);
  rx_gate<D,5>(re, im, gcT);
  rx_gate<D,6>(re, im, gcT);
  rx_gate<D,7>(re, im, gcT);
  rx_gate<D,8>(re, im, gcT);
  rx_gate<D,9>(re, im, gcT);
  if constexpr (D <= 4){
    const float2* __restrict__ pp = phase2 + (size_t)(D-1)*1024 + l5*32;
    #pragma unroll
    for (int r = 0; r < 32; ++r){
      float2 ph = pp[r];
      f32x2 cp = bc(ph.x), sp = bc(ph.y);
      f32x2 ar = re[r], ai = im[r];
      re[r] = fma2(-sp, ai, cp*ar);
      im[r] = fma2( sp, ar, cp*ai);
    }
  }
}

// ---- K2: one wave per FOUR samples + fused deterministic BN partials ----
__global__ __launch_bounds__(256) void k2_qsim(
    const float* __restrict__ enc, const unsigned* __restrict__ gkey,
    const float4* __restrict__ U0, const float* __restrict__ gcT,
    const float2* __restrict__ phase2,
    const float* __restrict__ fcWs, const float* __restrict__ fcB,
    float* __restrict__ outB, unsigned long long* __restrict__ cnt)
{
  int tid  = threadIdx.x;
  int lane = tid & 63;
  int wid  = tid >> 6;
  int l5   = lane & 31;
  int sA   = blockIdx.x * 16 + wid * 4 + ((lane >> 5) << 1);
  int sB   = sA + 1;

  float invr = 3.14159265358979f / (funkey(*gkey) + 1e-8f);

  f32x2 lr, li;
  #pragma unroll
  for (int j = 0; j < 4; ++j){
    int q = 5 + j;
    float angA = enc[(size_t)sA*NQ + q] * invr;
    float angB = enc[(size_t)sB*NQ + q] * invr;
    f32x2 cv = {__cosf(angA), __cosf(angB)};
    f32x2 sv = {__sinf(angA), __sinf(angB)};
    float4 a = U0[q*2+0], b = U0[q*2+1];
    f32x2 pa_r = fma2(bc(a.z), sv, bc(a.x)*cv);
    f32x2 pa_i = fma2(bc(a.w), sv, bc(a.y)*cv);
    f32x2 pb_r = fma2(bc(b.z), sv, bc(b.x)*cv);
    f32x2 pb_i = fma2(bc(b.w), sv, bc(b.y)*cv);
    bool bit = (l5 >> j) & 1;
    f32x2 fr = bit ? pb_r : pa_r;
    f32x2 fi = bit ? pb_i : pa_i;
    if (j == 0){ lr = fr; li = fi; }
    else {
      f32x2 t = lr*fr - li*fi;
      li = fma2(lr, fi, li*fr);
      lr = t;
    }
  }

  f32x2 A0r, A0i, A1r, A1i;
  {
    float angA = enc[(size_t)sA*NQ + 9] * invr;
    float angB = enc[(size_t)sB*NQ + 9] * invr;
    f32x2 cv = {__cosf(angA), __cosf(angB)};
    f32x2 sv = {__sinf(angA), __sinf(angB)};
    float4 a = U0[18], b = U0[19];
    f32x2 pa_r = fma2(bc(a.z), sv, bc(a.x)*cv);
    f32x2 pa_i = fma2(bc(a.w), sv, bc(a.y)*cv);
    f32x2 pb_r = fma2(bc(b.z), sv, bc(b.x)*cv);
    f32x2 pb_i = fma2(bc(b.w), sv, bc(b.y)*cv);
    bool e = ((l5 >> 4) ^ __popc(l5 & 15)) & 1;
    A0r = e ? pb_r : pa_r;  A0i = e ? pb_i : pa_i;
    A1r = e ? pa_r : pb_r;  A1i = e ? pa_i : pb_i;
  }

  f32x2 re[32], im[32];
  re[0] = lr; im[0] = li;
  #pragma unroll
  for (int k = 0; k < 5; ++k){
    float angA = enc[(size_t)sA*NQ + k] * invr;
    float angB = enc[(size_t)sB*NQ + k] * invr;
    f32x2 cv = {__cosf(angA), __cosf(angB)};
    f32x2 sv = {__sinf(angA), __sinf(angB)};
    float4 a = U0[k*2+0], b = U0[k*2+1];
    f32x2 pa_r = fma2(bc(a.z), sv, bc(a.x)*cv);
    f32x2 pa_i = fma2(bc(a.w), sv, bc(a.y)*cv);
    f32x2 pb_r = fma2(bc(b.z), sv, bc(b.x)*cv);
    f32x2 pb_i = fma2(bc(b.w), sv, bc(b.y)*cv);
    int w = 1 << k;
    #pragma unroll
    for (int r = 0; r < 16; ++r) if (r < w){
      f32x2 xr = re[r], xi = im[r];
      re[r|w] = xr*pb_r - xi*pb_i;
      im[r|w] = fma2(xr, pb_i, xi*pb_r);
      re[r]   = xr*pa_r - xi*pa_i;
      im[r]   = fma2(xr, pa_i, xi*pa_r);
    }
  }
  #pragma unroll
  for (int r = 0; r < 32; ++r){
    f32x2 sr = (__builtin_popcount(r) & 1) ? A1r : A0r;
    f32x2 si = (__builtin_popcount(r) & 1) ? A1i : A0i;
    f32x2 xr = re[r], xi = im[r];
    re[r] = xr*sr - xi*si;
    im[r] = fma2(xr, si, xi*sr);
  }

  run_layer<1>(re, im, gcT, phase2, l5);
  run_layer<2>(re, im, gcT, phase2, l5);
  run_layer<3>(re, im, gcT, phase2, l5);
  run_layer<4>(re, im, gcT, phase2, l5);
  run_layer<5>(re, im, gcT, phase2, l5);

  f32x2 p2[32];
  #pragma unroll
  for (int r = 0; r < 32; ++r) p2[r] = fma2(re[r], re[r], im[r]*im[r]);
  #pragma unroll
  for (int k = 0; k < 5; ++k){
    int w = 1 << k;
    #pragma unroll
    for (int r = 0; r < 32; ++r) if (!(r & w)){
      f32x2 a = p2[r], b = p2[r|w];
      p2[r] = a + b; p2[r|w] = a - b;
    }
  }
  f32x2 o2[4] = {{0.f,0.f},{0.f,0.f},{0.f,0.f},{0.f,0.f}};
  #pragma unroll
  for (int q = 0; q < NQ; ++q){
    constexpr int RALL[NQ] = {FT5(TAB.meas[0]),FT5(TAB.meas[1]),FT5(TAB.meas[2]),
                              FT5(TAB.meas[3]),FT5(TAB.meas[4]),FT5(TAB.meas[5]),
                              FT5(TAB.meas[6]),FT5(TAB.meas[7]),FT5(TAB.meas[8]),
                              FT5(TAB.meas[9])};
    int R = RALL[q];
    f32x2 tq = p2[R & 31];
    unsigned sg = (unsigned)(__popc((R >> 5) & l5) << 31);
    tq.x = __uint_as_float(__float_as_uint(tq.x) ^ sg);
    tq.y = __uint_as_float(__float_as_uint(tq.y) ^ sg);
    #pragma unroll
    for (int j = 0; j < 4; ++j) o2[j] = fma2(tq, bc(fcWs[j*NQ + q]), o2[j]);
  }
  #pragma unroll
  for (int j = 0; j < 4; ++j){
    o2[j].x += lxs<1>(o2[j].x);   o2[j].y += lxs<1>(o2[j].y);
    o2[j].x += lxs<2>(o2[j].x);   o2[j].y += lxs<2>(o2[j].y);
    o2[j].x += lxs<4>(o2[j].x);   o2[j].y += lxs<4>(o2[j].y);
    o2[j].x += lxs<8>(o2[j].x);   o2[j].y += lxs<8>(o2[j].y);
    o2[j].x += dsswz<16>(o2[j].x);
    o2[j].y += dsswz<16>(o2[j].y);
  }

  // ---- write outputs + deterministic BN partials ----
  __shared__ float sred[8][8];
  if (l5 == 0){
    float4 a4 = make_float4(o2[0].x+fcB[0], o2[1].x+fcB[1], o2[2].x+fcB[2], o2[3].x+fcB[3]);
    float4 b4 = make_float4(o2[0].y+fcB[0], o2[1].y+fcB[1], o2[2].y+fcB[2], o2[3].y+fcB[3]);
    *reinterpret_cast<float4*>(&outB[(size_t)sA*4]) = a4;
    *reinterpret_cast<float4*>(&outB[(size_t)sB*4]) = b4;
    int slot = wid * 2 + (lane >> 5);
    sred[slot][0] = a4.x + b4.x;  sred[slot][4] = a4.x*a4.x + b4.x*b4.x;
    sred[slot][1] = a4.y + b4.y;  sred[slot][5] = a4.y*a4.y + b4.y*b4.y;
    sred[slot][2] = a4.z + b4.z;  sred[slot][6] = a4.z*a4.z + b4.z*b4.z;
    sred[slot][3] = a4.w + b4.w;  sred[slot][7] = a4.w*a4.w + b4.w*b4.w;
  }
  __syncthreads();
  if (tid < 8){
    float s = 0.f;
    #pragma unroll
    for (int k = 0; k < 8; ++k) s += sred[k][tid];   // fixed order: deterministic
    long long iv = llrintf(s * ((tid < 4) ? SCALE_S : SCALE_Q));
    atomicAdd(&cnt[tid], (unsigned long long)iv);    // int add: order-free
  }
}

// ---- K4: reconstruct stats from int counters + apply BN (256 blocks) ----
__global__ __launch_bounds__(256) void k4_bn(const float* __restrict__ outB,
    const unsigned long long* __restrict__ cnt,
    const float* __restrict__ gamma, const float* __restrict__ beta,
    float* __restrict__ out)
{
  int idx = blockIdx.x * 256 + threadIdx.x;
  int c = idx & 3;
  double s = (double)(long long)cnt[c]     * (1.0 / (double)SCALE_S);
  double q = (double)(long long)cnt[4 + c] * (1.0 / (double)SCALE_Q);
  double m = s * (1.0 / B_SZ);
  double v = q * (1.0 / B_SZ) - m * m;
  float mean = (float)m;
  float rstd = (float)(1.0 / sqrt(v + 1e-5));
  float val = outB[idx];
  out[idx] = fmaf(gamma[c] * (val - mean), rstd, beta[c]);
}

extern "C" void kernel_launch(void* const* d_in, const int* in_sizes, int n_in,
                              void* d_out, int out_size, void* d_ws, size_t ws_size,
                              hipStream_t stream)
{
  const float* x     = (const float*)d_in[0];
  const float* encW  = (const float*)d_in[1];
  const float* encB  = (const float*)d_in[2];
  const float* wts   = (const float*)d_in[3];
  const float* fcW   = (const float*)d_in[4];
  const float* fcB   = (const float*)d_in[5];
  const float* gamma = (const float*)d_in[6];
  const float* beta  = (const float*)d_in[7];

  char* ws = (char*)d_ws;
  unsigned* gkey            = (unsigned*)ws;            // 4 B
  unsigned long long* cnt   = (unsigned long long*)(ws + 8);  // 64 B
  float4*  U0     = (float4*)(ws + 256);                // 320 B
  float*   gcT    = (float*)(ws + 1024);                // 200 B
  float*   fcWs   = (float*)(ws + 2048);                // 160 B
  float2*  phase  = (float2*)(ws + 4096);               // 32 KB (c,s)
  float*   enc    = (float*)(ws + 4096 + 65536);
  float*   outB   = (float*)(ws + 4096 + 65536 + (size_t)B_SZ*NQ*4);

  hipMemsetAsync(ws, 0, 128, stream);    // gkey + counters
  hipLaunchKernelGGL(k1_encode_prep, dim3(B_SZ/16), dim3(256), 0, stream,
                     x, encW, encB, wts, fcW, U0, gcT, phase, fcWs, enc, gkey);
  hipLaunchKernelGGL(k2_qsim, dim3(B_SZ/16), dim3(256), 0, stream,
                     enc, gkey, U0, gcT, phase, fcWs, fcB, outB, cnt);
  hipLaunchKernelGGL(k4_bn, dim3(B_SZ*4/256), dim3(256), 0, stream,
                     outB, cnt, gamma, beta, (float*)d_out);
}